// Round 3
// baseline (688.686 us; speedup 1.0000x reference)
//
#include <hip/hip_runtime.h>
#include <hip/hip_bf16.h>

typedef __attribute__((ext_vector_type(8))) short short8;
typedef __attribute__((ext_vector_type(16))) float floatx16;
typedef __attribute__((ext_vector_type(4))) float floatx4;

#define AS1 __attribute__((address_space(1)))
#define AS3 __attribute__((address_space(3)))

constexpr int MM = 65536;   // batch
constexpr int KK = 512;     // inner dim
constexpr int NN = 512;     // out dim per layer

#define GM 128
#define GN 128
#define GK 32
#define LDT 40   // logits kernel LDS row stride (shorts)

// round-to-nearest-even fp32 -> bf16 (bit-level, finite inputs)
__device__ __forceinline__ unsigned short bf16_rn(float v) {
  unsigned u = __float_as_uint(v);
  return (unsigned short)((u + 0x7FFFu + ((u >> 16) & 1u)) >> 16);
}
__device__ __forceinline__ float bf16_to_f32(unsigned short h) {
  return __uint_as_float((unsigned)h << 16);
}

// src fp32 -> (hi, lo) bf16 arrays. n4 = element count / 4.
__global__ __launch_bounds__(256) void split_kernel(
    const float* __restrict__ src, unsigned short* __restrict__ h,
    unsigned short* __restrict__ l, int n4) {
  int i = blockIdx.x * 256 + threadIdx.x;
  if (i >= n4) return;
  float4 v = ((const float4*)src)[i];
  ushort4 hv, lv;
  hv.x = bf16_rn(v.x); lv.x = bf16_rn(v.x - bf16_to_f32(hv.x));
  hv.y = bf16_rn(v.y); lv.y = bf16_rn(v.y - bf16_to_f32(hv.y));
  hv.z = bf16_rn(v.z); lv.z = bf16_rn(v.z - bf16_to_f32(hv.z));
  hv.w = bf16_rn(v.w); lv.w = bf16_rn(v.w - bf16_to_f32(hv.w));
  ((ushort4*)h)[i] = hv;
  ((ushort4*)l)[i] = lv;
}

// C[M,N] = act(A @ W^T + bias) via 3-term split-bf16 MFMA.
// R6: counted-vmcnt pipeline (raw s_barrier x2, s_waitcnt vmcnt(8) waits only
// the tile issued one full iteration ago; just-issued prefetch stays in flight
// across both barriers) + coalesced C epilogue via LDS (full-line stores, no
// write-allocate RMW).
// Swizzle (R5-verified at read floor): phys chunk p of row r holds logical
// chunk p ^ ((r>>1)&3).
template<bool RELU, bool SPLIT>
__global__ __launch_bounds__(256, 2) void gemm_mfma(
    const unsigned short* __restrict__ Ah, const unsigned short* __restrict__ Al,
    const unsigned short* __restrict__ Wh, const unsigned short* __restrict__ Wl,
    const float* __restrict__ bias,
    unsigned short* __restrict__ Ch, unsigned short* __restrict__ Cl,
    float* __restrict__ Cf) {
  __shared__ __align__(16) unsigned short smem[32768];   // 64 KB
  unsigned short* sAh = smem;            // [2][128][32]
  unsigned short* sAl = smem + 8192;
  unsigned short* sBh = smem + 16384;
  unsigned short* sBl = smem + 24576;
  const int tid = threadIdx.x;
  const int lane = tid & 63;
  const int wid = tid >> 6;
  const int wr = wid >> 1;
  const int wc = wid & 1;
  const int bm = blockIdx.x, bn = blockIdx.y;
  const size_t Abase = (size_t)bm * GM * KK;
  const size_t Bbase = (size_t)bn * GN * KK;

  // wave -> staged array (8 x 1KiB global_load_lds per wave per K-step)
  const unsigned short* gsrc; unsigned short* ldst; size_t tb;
  if (wid == 0)      { gsrc = Ah; tb = Abase; ldst = sAh; }
  else if (wid == 1) { gsrc = Al; tb = Abase; ldst = sAl; }
  else if (wid == 2) { gsrc = Wh; tb = Bbase; ldst = sBh; }
  else               { gsrc = Wl; tb = Bbase; ldst = sBl; }
  const int rowl = lane >> 2;                          // 0..15 in a 16-row segment
  const int gch  = (lane & 3) ^ ((lane >> 3) & 3);     // pre-swizzled source chunk
  const unsigned short* gbase = gsrc + tb + (size_t)rowl * KK + gch * 8;

  auto stage = [&](int buf, int kk) {
#pragma unroll
    for (int j = 0; j < 8; ++j) {
      __builtin_amdgcn_global_load_lds(
          (const AS1 unsigned int*)(gbase + (size_t)(j * 16) * KK + kk),
          (AS3 unsigned int*)(ldst + buf * 4096 + j * 16 * GK),
          16, 0, 0);
    }
  };

  floatx16 acc[2][2];
#pragma unroll
  for (int i = 0; i < 2; ++i)
#pragma unroll
    for (int j = 0; j < 2; ++j)
#pragma unroll
      for (int r = 0; r < 16; ++r) acc[i][j][r] = 0.f;

  stage(0, 0);

  const int swz = (lane >> 1) & 3;
  int cur = 0;
#pragma unroll
  for (int k0 = 0; k0 < KK; k0 += GK) {
    if (k0 + GK < KK) {
      stage(cur ^ 1, k0 + GK);                         // 8 loads stay in flight
      asm volatile("s_waitcnt vmcnt(8)" ::: "memory"); // wait tile-cur only
    } else {
      asm volatile("s_waitcnt vmcnt(0)" ::: "memory");
    }
    __builtin_amdgcn_s_barrier();                      // B1: tile-cur visible
    __builtin_amdgcn_sched_barrier(0);

    const unsigned short* pAh = sAh + cur * 4096;
    const unsigned short* pAl = sAl + cur * 4096;
    const unsigned short* pBh = sBh + cur * 4096;
    const unsigned short* pBl = sBl + cur * 4096;
#pragma unroll
    for (int ks = 0; ks < 2; ++ks) {
      const int ch = ks * 2 + (lane >> 5);       // wanted 16B chunk within row
      const int sw = (ch ^ swz) * 8;
      short8 fah[2], fal[2], fbh[2], fbl[2];
#pragma unroll
      for (int ri = 0; ri < 2; ++ri) {
        int row = wr * 64 + ri * 32 + (lane & 31);
        fah[ri] = *(const short8*)(pAh + row * GK + sw);
        fal[ri] = *(const short8*)(pAl + row * GK + sw);
      }
#pragma unroll
      for (int si = 0; si < 2; ++si) {
        int col = wc * 64 + si * 32 + (lane & 31);
        fbh[si] = *(const short8*)(pBh + col * GK + sw);
        fbl[si] = *(const short8*)(pBl + col * GK + sw);
      }
#pragma unroll
      for (int ri = 0; ri < 2; ++ri)
#pragma unroll
        for (int si = 0; si < 2; ++si) {
          acc[ri][si] = __builtin_amdgcn_mfma_f32_32x32x16_bf16(fah[ri], fbh[si], acc[ri][si], 0, 0, 0);
          acc[ri][si] = __builtin_amdgcn_mfma_f32_32x32x16_bf16(fah[ri], fbl[si], acc[ri][si], 0, 0, 0);
          acc[ri][si] = __builtin_amdgcn_mfma_f32_32x32x16_bf16(fal[ri], fbh[si], acc[ri][si], 0, 0, 0);
        }
    }
    __builtin_amdgcn_sched_barrier(0);
    __builtin_amdgcn_s_barrier();                      // B2: reads done -> re-stage ok
    cur ^= 1;
  }

  if (SPLIT) {
    // ---- coalesced C epilogue: pack (h|l<<16) into LDS, full-line stores ----
    unsigned* lds32 = (unsigned*)smem;                 // [128][128] x 4B = 64 KB
#pragma unroll
    for (int si = 0; si < 2; ++si) {
      int colL = wc * 64 + si * 32 + (lane & 31);
      float bv = bias[bn * GN + colL];
#pragma unroll
      for (int ri = 0; ri < 2; ++ri) {
#pragma unroll
        for (int r = 0; r < 16; ++r) {
          int rowL = wr * 64 + ri * 32 + (r & 3) + 8 * (r >> 2) + 4 * (lane >> 5);
          float v = acc[ri][si][r] + bv;
          if (RELU) v = fmaxf(v, 0.f);
          unsigned short h = bf16_rn(v);
          unsigned short lo = bf16_rn(v - bf16_to_f32(h));
          lds32[rowL * 128 + colL] = (unsigned)h | ((unsigned)lo << 16);
        }
      }
    }
    __syncthreads();
    const int rrow = tid >> 5;                         // 0..7
    const int rcol4 = (tid & 31) * 4;                  // 4 cols per thread
#pragma unroll
    for (int p = 0; p < 16; ++p) {
      int row = p * 8 + rrow;
      uint4 d = *(const uint4*)&lds32[row * 128 + rcol4];
      ushort4 hv, lv;
      hv.x = (unsigned short)(d.x); lv.x = (unsigned short)(d.x >> 16);
      hv.y = (unsigned short)(d.y); lv.y = (unsigned short)(d.y >> 16);
      hv.z = (unsigned short)(d.z); lv.z = (unsigned short)(d.z >> 16);
      hv.w = (unsigned short)(d.w); lv.w = (unsigned short)(d.w >> 16);
      size_t gi = (size_t)(bm * GM + row) * NN + bn * GN + rcol4;
      *(ushort4*)&Ch[gi] = hv;                         // 32 thr x 8B = 256B/row
      *(ushort4*)&Cl[gi] = lv;
    }
  } else {
#pragma unroll
    for (int si = 0; si < 2; ++si) {
      int col = bn * GN + wc * 64 + si * 32 + (lane & 31);
      float bv = bias[col];
#pragma unroll
      for (int ri = 0; ri < 2; ++ri) {
#pragma unroll
        for (int r = 0; r < 16; ++r) {
          int row = bm * GM + wr * 64 + ri * 32 + (r & 3) + 8 * (r >> 2) + 4 * (lane >> 5);
          float v = acc[ri][si][r] + bv;
          if (RELU) v = fmaxf(v, 0.f);
          Cf[(size_t)row * NN + col] = v;
        }
      }
    }
  }
}

// H2+H3 fused: mu = mh @ wgh^T + wgb (1-term bf16), then write only the
// y-selected class columns: z[b,e] = mu[b, y_b*16+e]. Counted-vmcnt pipeline.
__global__ __launch_bounds__(256, 2) void gemm_muz(
    const unsigned short* __restrict__ Ahm, const unsigned short* __restrict__ Wh,
    const float* __restrict__ bias, const float* __restrict__ y_in,
    float* __restrict__ z_out) {
  __shared__ __align__(16) unsigned short smem[16384];   // 32 KB
  unsigned short* sA = smem;             // [2][128][32]
  unsigned short* sB = smem + 8192;
  const int tid = threadIdx.x;
  const int lane = tid & 63;
  const int wid = tid >> 6;
  const int wr = wid >> 1;
  const int wc = wid & 1;
  const int bm = blockIdx.x, bn = blockIdx.y;
  const size_t Abase = (size_t)bm * GM * KK;
  const size_t Bbase = (size_t)bn * GN * KK;

  const unsigned short* gsrc = (wid < 2) ? Ahm : Wh;
  const size_t tb = (wid < 2) ? Abase : Bbase;
  unsigned short* ldst = (wid < 2) ? sA : sB;
  const int rbase = (wid & 1) * 64;
  const int rowl = lane >> 2;
  const int gch  = (lane & 3) ^ ((lane >> 3) & 3);
  const unsigned short* gbase = gsrc + tb + (size_t)rowl * KK + gch * 8;

  auto stage = [&](int buf, int kk) {
#pragma unroll
    for (int j = 0; j < 4; ++j) {
      const int r0 = rbase + j * 16;
      __builtin_amdgcn_global_load_lds(
          (const AS1 unsigned int*)(gbase + (size_t)r0 * KK + kk),
          (AS3 unsigned int*)(ldst + buf * 4096 + r0 * GK),
          16, 0, 0);
    }
  };

  floatx16 acc[2][2];
#pragma unroll
  for (int i = 0; i < 2; ++i)
#pragma unroll
    for (int j = 0; j < 2; ++j)
#pragma unroll
      for (int r = 0; r < 16; ++r) acc[i][j][r] = 0.f;

  stage(0, 0);

  const int swz = (lane >> 1) & 3;
  int cur = 0;
#pragma unroll
  for (int k0 = 0; k0 < KK; k0 += GK) {
    if (k0 + GK < KK) {
      stage(cur ^ 1, k0 + GK);
      asm volatile("s_waitcnt vmcnt(4)" ::: "memory");
    } else {
      asm volatile("s_waitcnt vmcnt(0)" ::: "memory");
    }
    __builtin_amdgcn_s_barrier();
    __builtin_amdgcn_sched_barrier(0);

    const unsigned short* pA = sA + cur * 4096;
    const unsigned short* pB = sB + cur * 4096;
#pragma unroll
    for (int ks = 0; ks < 2; ++ks) {
      const int ch = ks * 2 + (lane >> 5);
      const int sw = (ch ^ swz) * 8;
      short8 fa[2], fb[2];
#pragma unroll
      for (int ri = 0; ri < 2; ++ri) {
        int row = wr * 64 + ri * 32 + (lane & 31);
        fa[ri] = *(const short8*)(pA + row * GK + sw);
      }
#pragma unroll
      for (int si = 0; si < 2; ++si) {
        int col = wc * 64 + si * 32 + (lane & 31);
        fb[si] = *(const short8*)(pB + col * GK + sw);
      }
#pragma unroll
      for (int ri = 0; ri < 2; ++ri)
#pragma unroll
        for (int si = 0; si < 2; ++si)
          acc[ri][si] = __builtin_amdgcn_mfma_f32_32x32x16_bf16(fa[ri], fb[si], acc[ri][si], 0, 0, 0);
    }
    __builtin_amdgcn_sched_barrier(0);
    __builtin_amdgcn_s_barrier();
    cur ^= 1;
  }

  // epilogue: select-write. col -> class k=col>>4, latent e=col&15.
  int colv[2]; float bv[2];
#pragma unroll
  for (int si = 0; si < 2; ++si) {
    colv[si] = bn * GN + wc * 64 + si * 32 + (lane & 31);
    bv[si] = bias[colv[si]];
  }
#pragma unroll
  for (int ri = 0; ri < 2; ++ri)
#pragma unroll
    for (int r = 0; r < 16; ++r) {
      int row = bm * GM + wr * 64 + ri * 32 + (r & 3) + 8 * (r >> 2) + 4 * (lane >> 5);
      int yv = (int)y_in[row];
#pragma unroll
      for (int si = 0; si < 2; ++si) {
        if ((colv[si] >> 4) == yv)
          z_out[(size_t)row * 16 + (colv[si] & 15)] = acc[ri][si][r] + bv[si];
      }
    }
}

// H1: logits[65536,16] = (mh+ml) @ (wch+wcl)^T + bc via 3-term 16x16x32 MFMA,
// then per-row argmax -> y. A: row=lane&15, k=(lane>>4)*8+j; B symmetric;
// C/D: col=lane&15, row=(lane>>4)*4+reg  [m89/m91 verified].
__global__ __launch_bounds__(256) void logits_kernel(
    const unsigned short* __restrict__ mh, const unsigned short* __restrict__ ml,
    const unsigned short* __restrict__ wch, const unsigned short* __restrict__ wcl,
    const float* __restrict__ bc, float* __restrict__ y_out) {
  __shared__ unsigned short smh[64][LDT], sml[64][LDT];
  __shared__ float slog[64][17];
  const int tid = threadIdx.x;
  const int lane = tid & 63;
  const int wid = tid >> 6;            // wave -> rows wid*16..+16
  const size_t row0 = (size_t)blockIdx.x * 64;
  const int fr = lane & 15;
  const int fq = lane >> 4;

  floatx4 acc = {0.f, 0.f, 0.f, 0.f};
  const unsigned short* bh = wch + fr * 512 + fq * 8;   // Wc-split: 32 KB, L1/L2-hot
  const unsigned short* bl = wcl + fr * 512 + fq * 8;

  for (int k0 = 0; k0 < 512; k0 += 32) {
    {
      int row = tid >> 2, cc = (tid & 3) * 8;          // 256 chunks = 64 rows x 4
      size_t g = (row0 + row) * 512 + k0 + cc;
      *(short8*)&smh[row][cc] = *(const short8*)(mh + g);
      *(short8*)&sml[row][cc] = *(const short8*)(ml + g);
    }
    __syncthreads();
    short8 ah = *(const short8*)&smh[wid * 16 + fr][fq * 8];
    short8 al = *(const short8*)&sml[wid * 16 + fr][fq * 8];
    short8 fbh = *(const short8*)(bh + k0);
    short8 fbl = *(const short8*)(bl + k0);
    acc = __builtin_amdgcn_mfma_f32_16x16x32_bf16(ah, fbh, acc, 0, 0, 0);
    acc = __builtin_amdgcn_mfma_f32_16x16x32_bf16(ah, fbl, acc, 0, 0, 0);
    acc = __builtin_amdgcn_mfma_f32_16x16x32_bf16(al, fbh, acc, 0, 0, 0);
    __syncthreads();
  }
#pragma unroll
  for (int r = 0; r < 4; ++r)
    slog[wid * 16 + fq * 4 + r][fr] = acc[r] + bc[fr];
  __syncthreads();
  if (tid < 64) {
    float best = slog[tid][0];
    int bi = 0;
#pragma unroll
    for (int j = 1; j < 16; ++j) {     // strict >: first-max, matches np argmax
      float v = slog[tid][j];
      if (v > best) { best = v; bi = j; }
    }
    y_out[row0 + tid] = (float)bi;
  }
}

// prep: Wg[16,32,512] mu-rows -> wgh[256,512] bf16; wgb[col]=bg[col/16,col%16]
__global__ __launch_bounds__(256) void prep_wg(
    const float* __restrict__ Wg, const float* __restrict__ bg,
    unsigned short* __restrict__ wgh, float* __restrict__ wgb) {
  int gid = blockIdx.x * 256 + threadIdx.x;    // 32768 threads x 4 elems
  if (gid >= 32768) return;
  int r = gid >> 7;
  int c4 = (gid & 127) * 4;
  int k = r >> 4, e = r & 15;
  float4 v = *(const float4*)(Wg + ((size_t)k * 32 + e) * 512 + c4);
  ushort4 h;
  h.x = bf16_rn(v.x); h.y = bf16_rn(v.y); h.z = bf16_rn(v.z); h.w = bf16_rn(v.w);
  *(ushort4*)(wgh + (size_t)r * 512 + c4) = h;
  if (c4 == 0) wgb[r] = bg[k * 32 + e];
}

extern "C" void kernel_launch(void* const* d_in, const int* in_sizes, int n_in,
                              void* d_out, int out_size, void* d_ws, size_t ws_size,
                              hipStream_t stream) {
  const float* x  = (const float*)d_in[0];
  const float* W0 = (const float*)d_in[1];
  const float* b0 = (const float*)d_in[2];
  const float* W1 = (const float*)d_in[3];
  const float* b1 = (const float*)d_in[4];
  const float* W2 = (const float*)d_in[5];
  const float* b2 = (const float*)d_in[6];
  const float* Wc = (const float*)d_in[7];
  const float* bc = (const float*)d_in[8];
  const float* Wg = (const float*)d_in[9];
  const float* bg = (const float*)d_in[10];

  const size_t NEL = (size_t)MM * KK;
  unsigned short* Ah = (unsigned short*)d_ws;           // 64 MiB each
  unsigned short* Al = Ah + NEL;
  unsigned short* Bh = Al + NEL;
  unsigned short* Bl = Bh + NEL;
  // After GEMM3 (out: Bh/Bl = m-split), Ah/Al regions are free:
  unsigned short* wch = Al;                             // 16 KB
  unsigned short* wcl = Al + 8192;                      // 16 KB
  unsigned short* wgh = Al + 16384;                     // 256 KB
  float* wgb = (float*)(Al + 16384 + 131072);           // 1 KB

  // W-layer splits staged in d_out (3 MiB < 4.5 MiB); dead once GEMM3 done,
  // then overwritten by z (gemm_muz).
  unsigned short* w0h = (unsigned short*)d_out;
  unsigned short* w0l = w0h + 262144;
  unsigned short* w1h = w0l + 262144;
  unsigned short* w1l = w1h + 262144;
  unsigned short* w2h = w1l + 262144;
  unsigned short* w2l = w2h + 262144;

  float* z_out = (float*)d_out;
  float* y_out = z_out + (size_t)MM * 16;               // at +4 MiB, clear of w-splits

  split_kernel<<<(int)(NEL / 4 / 256), 256, 0, stream>>>(x, Ah, Al, (int)(NEL / 4));
  split_kernel<<<256, 256, 0, stream>>>(W0, w0h, w0l, 65536);
  split_kernel<<<256, 256, 0, stream>>>(W1, w1h, w1l, 65536);
  split_kernel<<<256, 256, 0, stream>>>(W2, w2h, w2l, 65536);

  dim3 grid(MM / GM, NN / GN);
  gemm_mfma<true , true ><<<grid, 256, 0, stream>>>(Ah, Al, w0h, w0l, b0, Bh, Bl, nullptr);
  gemm_mfma<true , true ><<<grid, 256, 0, stream>>>(Bh, Bl, w1h, w1l, b1, Ah, Al, nullptr);
  gemm_mfma<false, true ><<<grid, 256, 0, stream>>>(Ah, Al, w2h, w2l, b2, Bh, Bl, nullptr);

  // head preps (Ah/Al free from here)
  split_kernel<<<8, 256, 0, stream>>>(Wc, wch, wcl, 2048);
  prep_wg<<<128, 256, 0, stream>>>(Wg, bg, wgh, wgb);

  logits_kernel<<<MM / 64, 256, 0, stream>>>(Bh, Bl, wch, wcl, bc, y_out);
  gemm_muz<<<dim3(MM / GM, 2), 256, 0, stream>>>(Bh, wgh, wgb, y_out, z_out);
}

// Round 4
// 660.725 us; speedup vs baseline: 1.0423x; 1.0423x over previous
//
#include <hip/hip_runtime.h>
#include <hip/hip_bf16.h>

typedef __attribute__((ext_vector_type(8))) short short8;
typedef __attribute__((ext_vector_type(16))) float floatx16;
typedef __attribute__((ext_vector_type(4))) float floatx4;

#define AS1 __attribute__((address_space(1)))
#define AS3 __attribute__((address_space(3)))

constexpr int MM = 65536;   // batch
constexpr int KK = 512;     // inner dim
constexpr int NN = 512;     // out dim per layer

#define GM 128
#define GN 128
#define GK 32
#define LDT 40   // logits kernel LDS row stride (shorts)

// round-to-nearest-even fp32 -> bf16 (bit-level, finite inputs)
__device__ __forceinline__ unsigned short bf16_rn(float v) {
  unsigned u = __float_as_uint(v);
  return (unsigned short)((u + 0x7FFFu + ((u >> 16) & 1u)) >> 16);
}
__device__ __forceinline__ float bf16_to_f32(unsigned short h) {
  return __uint_as_float((unsigned)h << 16);
}

// src fp32 -> (hi, lo) bf16 arrays. n4 = element count / 4.
__global__ __launch_bounds__(256) void split_kernel(
    const float* __restrict__ src, unsigned short* __restrict__ h,
    unsigned short* __restrict__ l, int n4) {
  int i = blockIdx.x * 256 + threadIdx.x;
  if (i >= n4) return;
  float4 v = ((const float4*)src)[i];
  ushort4 hv, lv;
  hv.x = bf16_rn(v.x); lv.x = bf16_rn(v.x - bf16_to_f32(hv.x));
  hv.y = bf16_rn(v.y); lv.y = bf16_rn(v.y - bf16_to_f32(hv.y));
  hv.z = bf16_rn(v.z); lv.z = bf16_rn(v.z - bf16_to_f32(hv.z));
  hv.w = bf16_rn(v.w); lv.w = bf16_rn(v.w - bf16_to_f32(hv.w));
  ((ushort4*)h)[i] = hv;
  ((ushort4*)l)[i] = lv;
}

// C[M,N] = act(A @ W^T + bias) via 3-term split-bf16 MFMA.
// R7: XCD-chunked 1-D grid, bn-inner: the 4 blocks sharing an A-panel run as
// adjacent slots on the SAME XCD -> A fetched from HBM once per panel (L2
// reuse), W L2-resident. Counted-vmcnt pipeline + coalesced LDS epilogue (R6).
// Swizzle (R5-verified at read floor): phys chunk p of row r holds logical
// chunk p ^ ((r>>1)&3).
template<bool RELU, bool SPLIT>
__global__ __launch_bounds__(256, 2) void gemm_mfma(
    const unsigned short* __restrict__ Ah, const unsigned short* __restrict__ Al,
    const unsigned short* __restrict__ Wh, const unsigned short* __restrict__ Wl,
    const float* __restrict__ bias,
    unsigned short* __restrict__ Ch, unsigned short* __restrict__ Cl,
    float* __restrict__ Cf) {
  __shared__ __align__(16) unsigned short smem[32768];   // 64 KB
  unsigned short* sAh = smem;            // [2][128][32]
  unsigned short* sAl = smem + 8192;
  unsigned short* sBh = smem + 16384;
  unsigned short* sBl = smem + 24576;
  const int tid = threadIdx.x;
  const int lane = tid & 63;
  const int wid = tid >> 6;
  const int wr = wid >> 1;
  const int wc = wid & 1;
  // XCD-chunked bijective swizzle (nwg % 8 == 0), bn-inner
  const int nwg = gridDim.x;
  const int hw  = blockIdx.x;
  const int logical = (hw & 7) * (nwg >> 3) + (hw >> 3);
  const int bm = logical >> 2, bn = logical & 3;
  const size_t Abase = (size_t)bm * GM * KK;
  const size_t Bbase = (size_t)bn * GN * KK;

  // wave -> staged array (8 x 1KiB global_load_lds per wave per K-step)
  const unsigned short* gsrc; unsigned short* ldst; size_t tb;
  if (wid == 0)      { gsrc = Ah; tb = Abase; ldst = sAh; }
  else if (wid == 1) { gsrc = Al; tb = Abase; ldst = sAl; }
  else if (wid == 2) { gsrc = Wh; tb = Bbase; ldst = sBh; }
  else               { gsrc = Wl; tb = Bbase; ldst = sBl; }
  const int rowl = lane >> 2;                          // 0..15 in a 16-row segment
  const int gch  = (lane & 3) ^ ((lane >> 3) & 3);     // pre-swizzled source chunk
  const unsigned short* gbase = gsrc + tb + (size_t)rowl * KK + gch * 8;

  auto stage = [&](int buf, int kk) {
#pragma unroll
    for (int j = 0; j < 8; ++j) {
      __builtin_amdgcn_global_load_lds(
          (const AS1 unsigned int*)(gbase + (size_t)(j * 16) * KK + kk),
          (AS3 unsigned int*)(ldst + buf * 4096 + j * 16 * GK),
          16, 0, 0);
    }
  };

  floatx16 acc[2][2];
#pragma unroll
  for (int i = 0; i < 2; ++i)
#pragma unroll
    for (int j = 0; j < 2; ++j)
#pragma unroll
      for (int r = 0; r < 16; ++r) acc[i][j][r] = 0.f;

  stage(0, 0);

  const int swz = (lane >> 1) & 3;
  int cur = 0;
#pragma unroll
  for (int k0 = 0; k0 < KK; k0 += GK) {
    if (k0 + GK < KK) {
      stage(cur ^ 1, k0 + GK);                         // 8 loads stay in flight
      asm volatile("s_waitcnt vmcnt(8)" ::: "memory"); // wait tile-cur only
    } else {
      asm volatile("s_waitcnt vmcnt(0)" ::: "memory");
    }
    __builtin_amdgcn_s_barrier();                      // B1: tile-cur visible
    __builtin_amdgcn_sched_barrier(0);

    const unsigned short* pAh = sAh + cur * 4096;
    const unsigned short* pAl = sAl + cur * 4096;
    const unsigned short* pBh = sBh + cur * 4096;
    const unsigned short* pBl = sBl + cur * 4096;
#pragma unroll
    for (int ks = 0; ks < 2; ++ks) {
      const int ch = ks * 2 + (lane >> 5);       // wanted 16B chunk within row
      const int sw = (ch ^ swz) * 8;
      short8 fah[2], fal[2], fbh[2], fbl[2];
#pragma unroll
      for (int ri = 0; ri < 2; ++ri) {
        int row = wr * 64 + ri * 32 + (lane & 31);
        fah[ri] = *(const short8*)(pAh + row * GK + sw);
        fal[ri] = *(const short8*)(pAl + row * GK + sw);
      }
#pragma unroll
      for (int si = 0; si < 2; ++si) {
        int col = wc * 64 + si * 32 + (lane & 31);
        fbh[si] = *(const short8*)(pBh + col * GK + sw);
        fbl[si] = *(const short8*)(pBl + col * GK + sw);
      }
#pragma unroll
      for (int ri = 0; ri < 2; ++ri)
#pragma unroll
        for (int si = 0; si < 2; ++si) {
          acc[ri][si] = __builtin_amdgcn_mfma_f32_32x32x16_bf16(fah[ri], fbh[si], acc[ri][si], 0, 0, 0);
          acc[ri][si] = __builtin_amdgcn_mfma_f32_32x32x16_bf16(fah[ri], fbl[si], acc[ri][si], 0, 0, 0);
          acc[ri][si] = __builtin_amdgcn_mfma_f32_32x32x16_bf16(fal[ri], fbh[si], acc[ri][si], 0, 0, 0);
        }
    }
    __builtin_amdgcn_sched_barrier(0);
    __builtin_amdgcn_s_barrier();                      // B2: reads done -> re-stage ok
    cur ^= 1;
  }

  if (SPLIT) {
    // ---- coalesced C epilogue: pack (h|l<<16) into LDS, full-line stores ----
    unsigned* lds32 = (unsigned*)smem;                 // [128][128] x 4B = 64 KB
#pragma unroll
    for (int si = 0; si < 2; ++si) {
      int colL = wc * 64 + si * 32 + (lane & 31);
      float bv = bias[bn * GN + colL];
#pragma unroll
      for (int ri = 0; ri < 2; ++ri) {
#pragma unroll
        for (int r = 0; r < 16; ++r) {
          int rowL = wr * 64 + ri * 32 + (r & 3) + 8 * (r >> 2) + 4 * (lane >> 5);
          float v = acc[ri][si][r] + bv;
          if (RELU) v = fmaxf(v, 0.f);
          unsigned short h = bf16_rn(v);
          unsigned short lo = bf16_rn(v - bf16_to_f32(h));
          lds32[rowL * 128 + colL] = (unsigned)h | ((unsigned)lo << 16);
        }
      }
    }
    __syncthreads();
    const int rrow = tid >> 5;                         // 0..7
    const int rcol4 = (tid & 31) * 4;                  // 4 cols per thread
#pragma unroll
    for (int p = 0; p < 16; ++p) {
      int row = p * 8 + rrow;
      uint4 d = *(const uint4*)&lds32[row * 128 + rcol4];
      ushort4 hv, lv;
      hv.x = (unsigned short)(d.x); lv.x = (unsigned short)(d.x >> 16);
      hv.y = (unsigned short)(d.y); lv.y = (unsigned short)(d.y >> 16);
      hv.z = (unsigned short)(d.z); lv.z = (unsigned short)(d.z >> 16);
      hv.w = (unsigned short)(d.w); lv.w = (unsigned short)(d.w >> 16);
      size_t gi = (size_t)(bm * GM + row) * NN + bn * GN + rcol4;
      *(ushort4*)&Ch[gi] = hv;                         // 32 thr x 8B = 256B/row
      *(ushort4*)&Cl[gi] = lv;
    }
  } else {
#pragma unroll
    for (int si = 0; si < 2; ++si) {
      int col = bn * GN + wc * 64 + si * 32 + (lane & 31);
      float bv = bias[col];
#pragma unroll
      for (int ri = 0; ri < 2; ++ri) {
#pragma unroll
        for (int r = 0; r < 16; ++r) {
          int row = bm * GM + wr * 64 + ri * 32 + (r & 3) + 8 * (r >> 2) + 4 * (lane >> 5);
          float v = acc[ri][si][r] + bv;
          if (RELU) v = fmaxf(v, 0.f);
          Cf[(size_t)row * NN + col] = v;
        }
      }
    }
  }
}

// H2+H3 fused: mu = mh @ wgh^T + wgb (1-term bf16), then write only the
// y-selected class columns: z[b,e] = mu[b, y_b*16+e]. Counted-vmcnt pipeline.
// R7: XCD-chunked swizzle, bn-inner (A-panel fetched once, not x2).
__global__ __launch_bounds__(256, 2) void gemm_muz(
    const unsigned short* __restrict__ Ahm, const unsigned short* __restrict__ Wh,
    const float* __restrict__ bias, const float* __restrict__ y_in,
    float* __restrict__ z_out) {
  __shared__ __align__(16) unsigned short smem[16384];   // 32 KB
  unsigned short* sA = smem;             // [2][128][32]
  unsigned short* sB = smem + 8192;
  const int tid = threadIdx.x;
  const int lane = tid & 63;
  const int wid = tid >> 6;
  const int wr = wid >> 1;
  const int wc = wid & 1;
  const int nwg = gridDim.x;
  const int hw  = blockIdx.x;
  const int logical = (hw & 7) * (nwg >> 3) + (hw >> 3);
  const int bm = logical >> 1, bn = logical & 1;
  const size_t Abase = (size_t)bm * GM * KK;
  const size_t Bbase = (size_t)bn * GN * KK;

  const unsigned short* gsrc = (wid < 2) ? Ahm : Wh;
  const size_t tb = (wid < 2) ? Abase : Bbase;
  unsigned short* ldst = (wid < 2) ? sA : sB;
  const int rbase = (wid & 1) * 64;
  const int rowl = lane >> 2;
  const int gch  = (lane & 3) ^ ((lane >> 3) & 3);
  const unsigned short* gbase = gsrc + tb + (size_t)rowl * KK + gch * 8;

  auto stage = [&](int buf, int kk) {
#pragma unroll
    for (int j = 0; j < 4; ++j) {
      const int r0 = rbase + j * 16;
      __builtin_amdgcn_global_load_lds(
          (const AS1 unsigned int*)(gbase + (size_t)r0 * KK + kk),
          (AS3 unsigned int*)(ldst + buf * 4096 + r0 * GK),
          16, 0, 0);
    }
  };

  floatx16 acc[2][2];
#pragma unroll
  for (int i = 0; i < 2; ++i)
#pragma unroll
    for (int j = 0; j < 2; ++j)
#pragma unroll
      for (int r = 0; r < 16; ++r) acc[i][j][r] = 0.f;

  stage(0, 0);

  const int swz = (lane >> 1) & 3;
  int cur = 0;
#pragma unroll
  for (int k0 = 0; k0 < KK; k0 += GK) {
    if (k0 + GK < KK) {
      stage(cur ^ 1, k0 + GK);
      asm volatile("s_waitcnt vmcnt(4)" ::: "memory");
    } else {
      asm volatile("s_waitcnt vmcnt(0)" ::: "memory");
    }
    __builtin_amdgcn_s_barrier();
    __builtin_amdgcn_sched_barrier(0);

    const unsigned short* pA = sA + cur * 4096;
    const unsigned short* pB = sB + cur * 4096;
#pragma unroll
    for (int ks = 0; ks < 2; ++ks) {
      const int ch = ks * 2 + (lane >> 5);
      const int sw = (ch ^ swz) * 8;
      short8 fa[2], fb[2];
#pragma unroll
      for (int ri = 0; ri < 2; ++ri) {
        int row = wr * 64 + ri * 32 + (lane & 31);
        fa[ri] = *(const short8*)(pA + row * GK + sw);
      }
#pragma unroll
      for (int si = 0; si < 2; ++si) {
        int col = wc * 64 + si * 32 + (lane & 31);
        fb[si] = *(const short8*)(pB + col * GK + sw);
      }
#pragma unroll
      for (int ri = 0; ri < 2; ++ri)
#pragma unroll
        for (int si = 0; si < 2; ++si)
          acc[ri][si] = __builtin_amdgcn_mfma_f32_32x32x16_bf16(fa[ri], fb[si], acc[ri][si], 0, 0, 0);
    }
    __builtin_amdgcn_sched_barrier(0);
    __builtin_amdgcn_s_barrier();
    cur ^= 1;
  }

  // epilogue: select-write. col -> class k=col>>4, latent e=col&15.
  int colv[2]; float bv[2];
#pragma unroll
  for (int si = 0; si < 2; ++si) {
    colv[si] = bn * GN + wc * 64 + si * 32 + (lane & 31);
    bv[si] = bias[colv[si]];
  }
#pragma unroll
  for (int ri = 0; ri < 2; ++ri)
#pragma unroll
    for (int r = 0; r < 16; ++r) {
      int row = bm * GM + wr * 64 + ri * 32 + (r & 3) + 8 * (r >> 2) + 4 * (lane >> 5);
      int yv = (int)y_in[row];
#pragma unroll
      for (int si = 0; si < 2; ++si) {
        if ((colv[si] >> 4) == yv)
          z_out[(size_t)row * 16 + (colv[si] & 15)] = acc[ri][si][r] + bv[si];
      }
    }
}

// H1: logits[65536,16] = (mh+ml) @ (wch+wcl)^T + bc via 3-term 16x16x32 MFMA,
// then per-row argmax -> y. A: row=lane&15, k=(lane>>4)*8+j; B symmetric;
// C/D: col=lane&15, row=(lane>>4)*4+reg  [m89/m91 verified].
__global__ __launch_bounds__(256) void logits_kernel(
    const unsigned short* __restrict__ mh, const unsigned short* __restrict__ ml,
    const unsigned short* __restrict__ wch, const unsigned short* __restrict__ wcl,
    const float* __restrict__ bc, float* __restrict__ y_out) {
  __shared__ unsigned short smh[64][LDT], sml[64][LDT];
  __shared__ float slog[64][17];
  const int tid = threadIdx.x;
  const int lane = tid & 63;
  const int wid = tid >> 6;            // wave -> rows wid*16..+16
  const size_t row0 = (size_t)blockIdx.x * 64;
  const int fr = lane & 15;
  const int fq = lane >> 4;

  floatx4 acc = {0.f, 0.f, 0.f, 0.f};
  const unsigned short* bh = wch + fr * 512 + fq * 8;   // Wc-split: 32 KB, L1/L2-hot
  const unsigned short* bl = wcl + fr * 512 + fq * 8;

  for (int k0 = 0; k0 < 512; k0 += 32) {
    {
      int row = tid >> 2, cc = (tid & 3) * 8;          // 256 chunks = 64 rows x 4
      size_t g = (row0 + row) * 512 + k0 + cc;
      *(short8*)&smh[row][cc] = *(const short8*)(mh + g);
      *(short8*)&sml[row][cc] = *(const short8*)(ml + g);
    }
    __syncthreads();
    short8 ah = *(const short8*)&smh[wid * 16 + fr][fq * 8];
    short8 al = *(const short8*)&sml[wid * 16 + fr][fq * 8];
    short8 fbh = *(const short8*)(bh + k0);
    short8 fbl = *(const short8*)(bl + k0);
    acc = __builtin_amdgcn_mfma_f32_16x16x32_bf16(ah, fbh, acc, 0, 0, 0);
    acc = __builtin_amdgcn_mfma_f32_16x16x32_bf16(ah, fbl, acc, 0, 0, 0);
    acc = __builtin_amdgcn_mfma_f32_16x16x32_bf16(al, fbh, acc, 0, 0, 0);
    __syncthreads();
  }
#pragma unroll
  for (int r = 0; r < 4; ++r)
    slog[wid * 16 + fq * 4 + r][fr] = acc[r] + bc[fr];
  __syncthreads();
  if (tid < 64) {
    float best = slog[tid][0];
    int bi = 0;
#pragma unroll
    for (int j = 1; j < 16; ++j) {     // strict >: first-max, matches np argmax
      float v = slog[tid][j];
      if (v > best) { best = v; bi = j; }
    }
    y_out[row0 + tid] = (float)bi;
  }
}

// prep: Wg[16,32,512] mu-rows -> wgh[256,512] bf16; wgb[col]=bg[col/16,col%16]
__global__ __launch_bounds__(256) void prep_wg(
    const float* __restrict__ Wg, const float* __restrict__ bg,
    unsigned short* __restrict__ wgh, float* __restrict__ wgb) {
  int gid = blockIdx.x * 256 + threadIdx.x;    // 32768 threads x 4 elems
  if (gid >= 32768) return;
  int r = gid >> 7;
  int c4 = (gid & 127) * 4;
  int k = r >> 4, e = r & 15;
  float4 v = *(const float4*)(Wg + ((size_t)k * 32 + e) * 512 + c4);
  ushort4 h;
  h.x = bf16_rn(v.x); h.y = bf16_rn(v.y); h.z = bf16_rn(v.z); h.w = bf16_rn(v.w);
  *(ushort4*)(wgh + (size_t)r * 512 + c4) = h;
  if (c4 == 0) wgb[r] = bg[k * 32 + e];
}

extern "C" void kernel_launch(void* const* d_in, const int* in_sizes, int n_in,
                              void* d_out, int out_size, void* d_ws, size_t ws_size,
                              hipStream_t stream) {
  const float* x  = (const float*)d_in[0];
  const float* W0 = (const float*)d_in[1];
  const float* b0 = (const float*)d_in[2];
  const float* W1 = (const float*)d_in[3];
  const float* b1 = (const float*)d_in[4];
  const float* W2 = (const float*)d_in[5];
  const float* b2 = (const float*)d_in[6];
  const float* Wc = (const float*)d_in[7];
  const float* bc = (const float*)d_in[8];
  const float* Wg = (const float*)d_in[9];
  const float* bg = (const float*)d_in[10];

  const size_t NEL = (size_t)MM * KK;
  unsigned short* Ah = (unsigned short*)d_ws;           // 64 MiB each
  unsigned short* Al = Ah + NEL;
  unsigned short* Bh = Al + NEL;
  unsigned short* Bl = Bh + NEL;
  // After GEMM3 (out: Bh/Bl = m-split), Ah/Al regions are free:
  unsigned short* wch = Al;                             // 16 KB
  unsigned short* wcl = Al + 8192;                      // 16 KB
  unsigned short* wgh = Al + 16384;                     // 256 KB
  float* wgb = (float*)(Al + 16384 + 131072);           // 1 KB

  // W-layer splits staged in d_out (3 MiB < 4.5 MiB); dead once GEMM3 done,
  // then overwritten by z (gemm_muz).
  unsigned short* w0h = (unsigned short*)d_out;
  unsigned short* w0l = w0h + 262144;
  unsigned short* w1h = w0l + 262144;
  unsigned short* w1l = w1h + 262144;
  unsigned short* w2h = w1l + 262144;
  unsigned short* w2l = w2h + 262144;

  float* z_out = (float*)d_out;
  float* y_out = z_out + (size_t)MM * 16;               // at +4 MiB, clear of w-splits

  split_kernel<<<(int)(NEL / 4 / 256), 256, 0, stream>>>(x, Ah, Al, (int)(NEL / 4));
  split_kernel<<<256, 256, 0, stream>>>(W0, w0h, w0l, 65536);
  split_kernel<<<256, 256, 0, stream>>>(W1, w1h, w1l, 65536);
  split_kernel<<<256, 256, 0, stream>>>(W2, w2h, w2l, 65536);

  const int ngrid = (MM / GM) * (NN / GN);              // 2048, %8==0
  gemm_mfma<true , true ><<<ngrid, 256, 0, stream>>>(Ah, Al, w0h, w0l, b0, Bh, Bl, nullptr);
  gemm_mfma<true , true ><<<ngrid, 256, 0, stream>>>(Bh, Bl, w1h, w1l, b1, Ah, Al, nullptr);
  gemm_mfma<false, true ><<<ngrid, 256, 0, stream>>>(Ah, Al, w2h, w2l, b2, Bh, Bl, nullptr);

  // head preps (Ah/Al free from here)
  split_kernel<<<8, 256, 0, stream>>>(Wc, wch, wcl, 2048);
  prep_wg<<<128, 256, 0, stream>>>(Wg, bg, wgh, wgb);

  logits_kernel<<<MM / 64, 256, 0, stream>>>(Bh, Bl, wch, wcl, bc, y_out);
  gemm_muz<<<(MM / GM) * 2, 256, 0, stream>>>(Bh, wgh, wgb, y_out, z_out);
}

// Round 5
// 624.246 us; speedup vs baseline: 1.1032x; 1.0584x over previous
//
#include <hip/hip_runtime.h>
#include <hip/hip_bf16.h>

typedef __attribute__((ext_vector_type(8))) short short8;
typedef __attribute__((ext_vector_type(16))) float floatx16;
typedef __attribute__((ext_vector_type(4))) float floatx4;

#define AS1 __attribute__((address_space(1)))
#define AS3 __attribute__((address_space(3)))

constexpr int MM = 65536;   // batch
constexpr int KK = 512;     // inner dim
constexpr int NN = 512;     // out dim per layer

#define GM 128
#define GN 128
#define GK 32
#define LDT 40   // logits kernel LDS row stride (shorts)

// round-to-nearest-even fp32 -> bf16 (bit-level, finite inputs)
__device__ __forceinline__ unsigned short bf16_rn(float v) {
  unsigned u = __float_as_uint(v);
  return (unsigned short)((u + 0x7FFFu + ((u >> 16) & 1u)) >> 16);
}
__device__ __forceinline__ float bf16_to_f32(unsigned short h) {
  return __uint_as_float((unsigned)h << 16);
}

// src fp32 -> (hi, lo) bf16 arrays. n4 = element count / 4.
__global__ __launch_bounds__(256) void split_kernel(
    const float* __restrict__ src, unsigned short* __restrict__ h,
    unsigned short* __restrict__ l, int n4) {
  int i = blockIdx.x * 256 + threadIdx.x;
  if (i >= n4) return;
  float4 v = ((const float4*)src)[i];
  ushort4 hv, lv;
  hv.x = bf16_rn(v.x); lv.x = bf16_rn(v.x - bf16_to_f32(hv.x));
  hv.y = bf16_rn(v.y); lv.y = bf16_rn(v.y - bf16_to_f32(hv.y));
  hv.z = bf16_rn(v.z); lv.z = bf16_rn(v.z - bf16_to_f32(hv.z));
  hv.w = bf16_rn(v.w); lv.w = bf16_rn(v.w - bf16_to_f32(hv.w));
  ((ushort4*)h)[i] = hv;
  ((ushort4*)l)[i] = lv;
}

// C[M,N] = act(A @ W^T + bias) via 3-term split-bf16 MFMA.
// R8: 256x256 tile, 512 thr = 8 waves (2M x 4N), GK=32, 128 KiB LDS dbuf.
// Per wave/K-step: 24 b128 reads for 48 MFMA (was 16 for 24) -- LDS:MFMA
// ratio 1.33x better, barriers/MFMA halved. Counted-vmcnt prefetch (depth=1
// full iter), per-ks phase {reads -> setprio MFMA cluster}, XCD-chunked grid,
// chunked [64][256] LDS epilogue with full-line stores.
// Swizzle (R5-verified): phys chunk p of row r holds logical p ^ ((r>>1)&3);
// for all frag rows this reduces to (lane>>1)&3, staging side (lane>>3)&3.
template<bool RELU>
__global__ __launch_bounds__(512, 1) void gemm_mfma(
    const unsigned short* __restrict__ Ah, const unsigned short* __restrict__ Al,
    const unsigned short* __restrict__ Wh, const unsigned short* __restrict__ Wl,
    const float* __restrict__ bias,
    unsigned short* __restrict__ Ch, unsigned short* __restrict__ Cl) {
  __shared__ __align__(16) unsigned short smem[65536];   // 128 KB
  // layout (shorts): [buf:2][array:4][256*32]; arrays: 0=Ah 1=Al 2=Bh 3=Bl
  const int tid = threadIdx.x;
  const int lane = tid & 63;
  const int wid = tid >> 6;          // 0..7
  const int wr = wid >> 2;           // 0..1 : 128-row half
  const int wc = wid & 3;            // 0..3 : 64-col strip
  // XCD-chunked bijective swizzle (nwg % 8 == 0), bn-inner
  const int nwg = gridDim.x;         // 512
  const int hw  = blockIdx.x;
  const int logical = (hw & 7) * (nwg >> 3) + (hw >> 3);
  const int bm = logical >> 1, bn = logical & 1;
  const size_t Abase = (size_t)bm * 256 * KK;
  const size_t Bbase = (size_t)bn * 256 * KK;

  // staging: wave w stages array (w>>1), row-half (w&1)*128 ; 8 x 1KiB each
  const int sarr  = wid >> 1;
  const int rbase = (wid & 1) * 128;
  const unsigned short* gsrc = (sarr == 0) ? Ah : (sarr == 1) ? Al
                             : (sarr == 2) ? Wh : Wl;
  const size_t tb = (sarr < 2) ? Abase : Bbase;
  const int rowl = lane >> 2;                          // 0..15 in 16-row seg
  const int gch  = (lane & 3) ^ ((lane >> 3) & 3);     // pre-swizzled chunk
  const unsigned short* gbase = gsrc + tb + (size_t)(rbase + rowl) * KK + gch * 8;
  unsigned short* ldst = smem + sarr * 8192 + rbase * 32;

  auto stage = [&](int buf, int kk) {
#pragma unroll
    for (int j = 0; j < 8; ++j) {
      __builtin_amdgcn_global_load_lds(
          (const AS1 unsigned int*)(gbase + (size_t)(j * 16) * KK + kk),
          (AS3 unsigned int*)(ldst + buf * 32768 + j * 16 * 32),
          16, 0, 0);
    }
  };

  floatx16 acc[4][2];
#pragma unroll
  for (int i = 0; i < 4; ++i)
#pragma unroll
    for (int j = 0; j < 2; ++j)
#pragma unroll
      for (int r = 0; r < 16; ++r) acc[i][j][r] = 0.f;

  stage(0, 0);

  const int swz = (lane >> 1) & 3;
  int cur = 0;
#pragma unroll
  for (int t = 0; t < 16; ++t) {
    if (t < 15) {
      stage(cur ^ 1, (t + 1) * GK);                    // 8 loads stay in flight
      asm volatile("s_waitcnt vmcnt(8)" ::: "memory"); // tile-cur landed
    } else {
      asm volatile("s_waitcnt vmcnt(0)" ::: "memory");
    }
    __builtin_amdgcn_s_barrier();                      // B1: tile-cur visible
    __builtin_amdgcn_sched_barrier(0);

    const unsigned short* base = smem + cur * 32768;
#pragma unroll
    for (int ks = 0; ks < 2; ++ks) {
      const int ch = ks * 2 + (lane >> 5);             // wanted 16B chunk
      const int sw = (ch ^ swz) * 8;
      short8 fah[4], fal[4], fbh[2], fbl[2];
#pragma unroll
      for (int ri = 0; ri < 4; ++ri) {
        int row = wr * 128 + ri * 32 + (lane & 31);
        fah[ri] = *(const short8*)(base + row * 32 + sw);
        fal[ri] = *(const short8*)(base + 8192 + row * 32 + sw);
      }
#pragma unroll
      for (int si = 0; si < 2; ++si) {
        int col = wc * 64 + si * 32 + (lane & 31);
        fbh[si] = *(const short8*)(base + 16384 + col * 32 + sw);
        fbl[si] = *(const short8*)(base + 24576 + col * 32 + sw);
      }
      __builtin_amdgcn_s_setprio(1);
#pragma unroll
      for (int ri = 0; ri < 4; ++ri)
#pragma unroll
        for (int si = 0; si < 2; ++si) {
          acc[ri][si] = __builtin_amdgcn_mfma_f32_32x32x16_bf16(fah[ri], fbh[si], acc[ri][si], 0, 0, 0);
          acc[ri][si] = __builtin_amdgcn_mfma_f32_32x32x16_bf16(fah[ri], fbl[si], acc[ri][si], 0, 0, 0);
          acc[ri][si] = __builtin_amdgcn_mfma_f32_32x32x16_bf16(fal[ri], fbh[si], acc[ri][si], 0, 0, 0);
        }
      __builtin_amdgcn_s_setprio(0);
    }
    __builtin_amdgcn_sched_barrier(0);
    __builtin_amdgcn_s_barrier();                      // B2: reads done
    cur ^= 1;
  }

  // ---- chunked coalesced epilogue: 4 passes of [64][256] packed (h|l<<16) ----
  float bv[2];
#pragma unroll
  for (int si = 0; si < 2; ++si)
    bv[si] = bias[bn * 256 + wc * 64 + si * 32 + (lane & 31)];

  unsigned* lds32 = (unsigned*)smem;                   // [64][256] = 64 KB
#pragma unroll
  for (int ri = 0; ri < 4; ++ri) {
    __syncthreads();                                   // lds32 free for reuse
#pragma unroll
    for (int si = 0; si < 2; ++si) {
      int lcol = wc * 64 + si * 32 + (lane & 31);
#pragma unroll
      for (int r = 0; r < 16; ++r) {
        int frow = (r & 3) + 8 * (r >> 2) + 4 * (lane >> 5);
        float v = acc[ri][si][r] + bv[si];
        if (RELU) v = fmaxf(v, 0.f);
        unsigned short h = bf16_rn(v);
        unsigned short lo = bf16_rn(v - bf16_to_f32(h));
        lds32[(wr * 32 + frow) * 256 + lcol] = (unsigned)h | ((unsigned)lo << 16);
      }
    }
    __syncthreads();
#pragma unroll
    for (int p = 0; p < 8; ++p) {
      int c = tid + p * 512;                           // 0..4095 uint4-chunks
      int lrow = c >> 6;
      int cc = (c & 63) * 4;
      uint4 d = *(const uint4*)&lds32[lrow * 256 + cc];
      ushort4 hv, lv;
      hv.x = (unsigned short)(d.x); lv.x = (unsigned short)(d.x >> 16);
      hv.y = (unsigned short)(d.y); lv.y = (unsigned short)(d.y >> 16);
      hv.z = (unsigned short)(d.z); lv.z = (unsigned short)(d.z >> 16);
      hv.w = (unsigned short)(d.w); lv.w = (unsigned short)(d.w >> 16);
      int grow = bm * 256 + (lrow >> 5) * 128 + ri * 32 + (lrow & 31);
      size_t gi = (size_t)grow * NN + bn * 256 + cc;
      *(ushort4*)&Ch[gi] = hv;                         // full-line bursts
      *(ushort4*)&Cl[gi] = lv;
    }
  }
}

// H2+H3 fused: mu = mh @ wgh^T + wgb (1-term bf16), then write only the
// y-selected class columns: z[b,e] = mu[b, y_b*16+e]. Counted-vmcnt pipeline.
// XCD-chunked swizzle, bn-inner (A-panel fetched once, not x2).
__global__ __launch_bounds__(256, 2) void gemm_muz(
    const unsigned short* __restrict__ Ahm, const unsigned short* __restrict__ Wh,
    const float* __restrict__ bias, const float* __restrict__ y_in,
    float* __restrict__ z_out) {
  __shared__ __align__(16) unsigned short smem[16384];   // 32 KB
  unsigned short* sA = smem;             // [2][128][32]
  unsigned short* sB = smem + 8192;
  const int tid = threadIdx.x;
  const int lane = tid & 63;
  const int wid = tid >> 6;
  const int wr = wid >> 1;
  const int wc = wid & 1;
  const int nwg = gridDim.x;
  const int hw  = blockIdx.x;
  const int logical = (hw & 7) * (nwg >> 3) + (hw >> 3);
  const int bm = logical >> 1, bn = logical & 1;
  const size_t Abase = (size_t)bm * GM * KK;
  const size_t Bbase = (size_t)bn * GN * KK;

  const unsigned short* gsrc = (wid < 2) ? Ahm : Wh;
  const size_t tb = (wid < 2) ? Abase : Bbase;
  unsigned short* ldst = (wid < 2) ? sA : sB;
  const int rbase = (wid & 1) * 64;
  const int rowl = lane >> 2;
  const int gch  = (lane & 3) ^ ((lane >> 3) & 3);
  const unsigned short* gbase = gsrc + tb + (size_t)rowl * KK + gch * 8;

  auto stage = [&](int buf, int kk) {
#pragma unroll
    for (int j = 0; j < 4; ++j) {
      const int r0 = rbase + j * 16;
      __builtin_amdgcn_global_load_lds(
          (const AS1 unsigned int*)(gbase + (size_t)r0 * KK + kk),
          (AS3 unsigned int*)(ldst + buf * 4096 + r0 * GK),
          16, 0, 0);
    }
  };

  floatx16 acc[2][2];
#pragma unroll
  for (int i = 0; i < 2; ++i)
#pragma unroll
    for (int j = 0; j < 2; ++j)
#pragma unroll
      for (int r = 0; r < 16; ++r) acc[i][j][r] = 0.f;

  stage(0, 0);

  const int swz = (lane >> 1) & 3;
  int cur = 0;
#pragma unroll
  for (int k0 = 0; k0 < KK; k0 += GK) {
    if (k0 + GK < KK) {
      stage(cur ^ 1, k0 + GK);
      asm volatile("s_waitcnt vmcnt(4)" ::: "memory");
    } else {
      asm volatile("s_waitcnt vmcnt(0)" ::: "memory");
    }
    __builtin_amdgcn_s_barrier();
    __builtin_amdgcn_sched_barrier(0);

    const unsigned short* pA = sA + cur * 4096;
    const unsigned short* pB = sB + cur * 4096;
#pragma unroll
    for (int ks = 0; ks < 2; ++ks) {
      const int ch = ks * 2 + (lane >> 5);
      const int sw = (ch ^ swz) * 8;
      short8 fa[2], fb[2];
#pragma unroll
      for (int ri = 0; ri < 2; ++ri) {
        int row = wr * 64 + ri * 32 + (lane & 31);
        fa[ri] = *(const short8*)(pA + row * GK + sw);
      }
#pragma unroll
      for (int si = 0; si < 2; ++si) {
        int col = wc * 64 + si * 32 + (lane & 31);
        fb[si] = *(const short8*)(pB + col * GK + sw);
      }
#pragma unroll
      for (int ri = 0; ri < 2; ++ri)
#pragma unroll
        for (int si = 0; si < 2; ++si)
          acc[ri][si] = __builtin_amdgcn_mfma_f32_32x32x16_bf16(fa[ri], fb[si], acc[ri][si], 0, 0, 0);
    }
    __builtin_amdgcn_sched_barrier(0);
    __builtin_amdgcn_s_barrier();
    cur ^= 1;
  }

  // epilogue: select-write. col -> class k=col>>4, latent e=col&15.
  int colv[2]; float bv[2];
#pragma unroll
  for (int si = 0; si < 2; ++si) {
    colv[si] = bn * GN + wc * 64 + si * 32 + (lane & 31);
    bv[si] = bias[colv[si]];
  }
#pragma unroll
  for (int ri = 0; ri < 2; ++ri)
#pragma unroll
    for (int r = 0; r < 16; ++r) {
      int row = bm * GM + wr * 64 + ri * 32 + (r & 3) + 8 * (r >> 2) + 4 * (lane >> 5);
      int yv = (int)y_in[row];
#pragma unroll
      for (int si = 0; si < 2; ++si) {
        if ((colv[si] >> 4) == yv)
          z_out[(size_t)row * 16 + (colv[si] & 15)] = acc[ri][si][r] + bv[si];
      }
    }
}

// H1: logits[65536,16] = (mh+ml) @ (wch+wcl)^T + bc via 3-term 16x16x32 MFMA,
// then per-row argmax -> y. A: row=lane&15, k=(lane>>4)*8+j; B symmetric;
// C/D: col=lane&15, row=(lane>>4)*4+reg  [m89/m91 verified].
__global__ __launch_bounds__(256) void logits_kernel(
    const unsigned short* __restrict__ mh, const unsigned short* __restrict__ ml,
    const unsigned short* __restrict__ wch, const unsigned short* __restrict__ wcl,
    const float* __restrict__ bc, float* __restrict__ y_out) {
  __shared__ unsigned short smh[64][LDT], sml[64][LDT];
  __shared__ float slog[64][17];
  const int tid = threadIdx.x;
  const int lane = tid & 63;
  const int wid = tid >> 6;            // wave -> rows wid*16..+16
  const size_t row0 = (size_t)blockIdx.x * 64;
  const int fr = lane & 15;
  const int fq = lane >> 4;

  floatx4 acc = {0.f, 0.f, 0.f, 0.f};
  const unsigned short* bh = wch + fr * 512 + fq * 8;   // Wc-split: 32 KB, L1/L2-hot
  const unsigned short* bl = wcl + fr * 512 + fq * 8;

  for (int k0 = 0; k0 < 512; k0 += 32) {
    {
      int row = tid >> 2, cc = (tid & 3) * 8;          // 256 chunks = 64 rows x 4
      size_t g = (row0 + row) * 512 + k0 + cc;
      *(short8*)&smh[row][cc] = *(const short8*)(mh + g);
      *(short8*)&sml[row][cc] = *(const short8*)(ml + g);
    }
    __syncthreads();
    short8 ah = *(const short8*)&smh[wid * 16 + fr][fq * 8];
    short8 al = *(const short8*)&sml[wid * 16 + fr][fq * 8];
    short8 fbh = *(const short8*)(bh + k0);
    short8 fbl = *(const short8*)(bl + k0);
    acc = __builtin_amdgcn_mfma_f32_16x16x32_bf16(ah, fbh, acc, 0, 0, 0);
    acc = __builtin_amdgcn_mfma_f32_16x16x32_bf16(ah, fbl, acc, 0, 0, 0);
    acc = __builtin_amdgcn_mfma_f32_16x16x32_bf16(al, fbh, acc, 0, 0, 0);
    __syncthreads();
  }
#pragma unroll
  for (int r = 0; r < 4; ++r)
    slog[wid * 16 + fq * 4 + r][fr] = acc[r] + bc[fr];
  __syncthreads();
  if (tid < 64) {
    float best = slog[tid][0];
    int bi = 0;
#pragma unroll
    for (int j = 1; j < 16; ++j) {     // strict >: first-max, matches np argmax
      float v = slog[tid][j];
      if (v > best) { best = v; bi = j; }
    }
    y_out[row0 + tid] = (float)bi;
  }
}

// prep: Wg[16,32,512] mu-rows -> wgh[256,512] bf16; wgb[col]=bg[col/16,col%16]
__global__ __launch_bounds__(256) void prep_wg(
    const float* __restrict__ Wg, const float* __restrict__ bg,
    unsigned short* __restrict__ wgh, float* __restrict__ wgb) {
  int gid = blockIdx.x * 256 + threadIdx.x;    // 32768 threads x 4 elems
  if (gid >= 32768) return;
  int r = gid >> 7;
  int c4 = (gid & 127) * 4;
  int k = r >> 4, e = r & 15;
  float4 v = *(const float4*)(Wg + ((size_t)k * 32 + e) * 512 + c4);
  ushort4 h;
  h.x = bf16_rn(v.x); h.y = bf16_rn(v.y); h.z = bf16_rn(v.z); h.w = bf16_rn(v.w);
  *(ushort4*)(wgh + (size_t)r * 512 + c4) = h;
  if (c4 == 0) wgb[r] = bg[k * 32 + e];
}

extern "C" void kernel_launch(void* const* d_in, const int* in_sizes, int n_in,
                              void* d_out, int out_size, void* d_ws, size_t ws_size,
                              hipStream_t stream) {
  const float* x  = (const float*)d_in[0];
  const float* W0 = (const float*)d_in[1];
  const float* b0 = (const float*)d_in[2];
  const float* W1 = (const float*)d_in[3];
  const float* b1 = (const float*)d_in[4];
  const float* W2 = (const float*)d_in[5];
  const float* b2 = (const float*)d_in[6];
  const float* Wc = (const float*)d_in[7];
  const float* bc = (const float*)d_in[8];
  const float* Wg = (const float*)d_in[9];
  const float* bg = (const float*)d_in[10];

  const size_t NEL = (size_t)MM * KK;
  unsigned short* Ah = (unsigned short*)d_ws;           // 64 MiB each
  unsigned short* Al = Ah + NEL;
  unsigned short* Bh = Al + NEL;
  unsigned short* Bl = Bh + NEL;
  // After GEMM3 (out: Bh/Bl = m-split), Ah/Al regions are free:
  unsigned short* wch = Al;                             // 16 KB
  unsigned short* wcl = Al + 8192;                      // 16 KB
  unsigned short* wgh = Al + 16384;                     // 256 KB
  float* wgb = (float*)(Al + 16384 + 131072);           // 1 KB

  // W-layer splits staged in d_out (3 MiB < 4.5 MiB); dead once GEMM3 done,
  // then overwritten by z (gemm_muz).
  unsigned short* w0h = (unsigned short*)d_out;
  unsigned short* w0l = w0h + 262144;
  unsigned short* w1h = w0l + 262144;
  unsigned short* w1l = w1h + 262144;
  unsigned short* w2h = w1l + 262144;
  unsigned short* w2l = w2h + 262144;

  float* z_out = (float*)d_out;
  float* y_out = z_out + (size_t)MM * 16;               // at +4 MiB, clear of w-splits

  split_kernel<<<(int)(NEL / 4 / 256), 256, 0, stream>>>(x, Ah, Al, (int)(NEL / 4));
  split_kernel<<<256, 256, 0, stream>>>(W0, w0h, w0l, 65536);
  split_kernel<<<256, 256, 0, stream>>>(W1, w1h, w1l, 65536);
  split_kernel<<<256, 256, 0, stream>>>(W2, w2h, w2l, 65536);

  const int ngrid = (MM / 256) * (NN / 256);            // 512, %8==0
  gemm_mfma<true ><<<ngrid, 512, 0, stream>>>(Ah, Al, w0h, w0l, b0, Bh, Bl);
  gemm_mfma<true ><<<ngrid, 512, 0, stream>>>(Bh, Bl, w1h, w1l, b1, Ah, Al);
  gemm_mfma<false><<<ngrid, 512, 0, stream>>>(Ah, Al, w2h, w2l, b2, Bh, Bl);

  // head preps (Ah/Al free from here)
  split_kernel<<<8, 256, 0, stream>>>(Wc, wch, wcl, 2048);
  prep_wg<<<128, 256, 0, stream>>>(Wg, bg, wgh, wgb);

  logits_kernel<<<MM / 64, 256, 0, stream>>>(Bh, Bl, wch, wcl, bc, y_out);
  gemm_muz<<<(MM / GM) * 2, 256, 0, stream>>>(Bh, wgh, wgb, y_out, z_out);
}

// Round 7
// 615.529 us; speedup vs baseline: 1.1189x; 1.0142x over previous
//
#include <hip/hip_runtime.h>
#include <hip/hip_bf16.h>

typedef __attribute__((ext_vector_type(8))) short short8;
typedef __attribute__((ext_vector_type(16))) float floatx16;
typedef __attribute__((ext_vector_type(4))) float floatx4;

#define AS1 __attribute__((address_space(1)))
#define AS3 __attribute__((address_space(3)))

constexpr int MM = 65536;   // batch
constexpr int KK = 512;     // inner dim
constexpr int NN = 512;     // out dim per layer

#define GM 128
#define GN 128
#define GK 32
#define LDT 40   // logits kernel LDS row stride (shorts)

// round-to-nearest-even fp32 -> bf16 (bit-level, finite inputs)
__device__ __forceinline__ unsigned short bf16_rn(float v) {
  unsigned u = __float_as_uint(v);
  return (unsigned short)((u + 0x7FFFu + ((u >> 16) & 1u)) >> 16);
}
__device__ __forceinline__ float bf16_to_f32(unsigned short h) {
  return __uint_as_float((unsigned)h << 16);
}

// src fp32 -> (hi, lo) bf16 arrays. n4 = element count / 4.
__global__ __launch_bounds__(256) void split_kernel(
    const float* __restrict__ src, unsigned short* __restrict__ h,
    unsigned short* __restrict__ l, int n4) {
  int i = blockIdx.x * 256 + threadIdx.x;
  if (i >= n4) return;
  float4 v = ((const float4*)src)[i];
  ushort4 hv, lv;
  hv.x = bf16_rn(v.x); lv.x = bf16_rn(v.x - bf16_to_f32(hv.x));
  hv.y = bf16_rn(v.y); lv.y = bf16_rn(v.y - bf16_to_f32(hv.y));
  hv.z = bf16_rn(v.z); lv.z = bf16_rn(v.z - bf16_to_f32(hv.z));
  hv.w = bf16_rn(v.w); lv.w = bf16_rn(v.w - bf16_to_f32(hv.w));
  ((ushort4*)h)[i] = hv;
  ((ushort4*)l)[i] = lv;
}

// C[M,N] = act(A @ W^T + bias) via 3-term split-bf16 MFMA.
// R9 (resubmit; R6 run was an infra failure): 4-phase interleaved schedule
// per K-tile (T3+T4+T5): phase p=(ks,h) reads only its fragments, issues 2
// of 8 prefetch gload_lds, sched_barrier-pinned s_barrier pair, setprio'd
// 12-MFMA cluster. vmcnt(2) once per K-tile (never 0 in main loop).
// 256x256 tile, 8 waves, GK=32, 128 KiB dbuf, XCD-chunked grid, chunked
// LDS epilogue (R8). Swizzle (R5-verified): phys chunk p of row r holds
// logical p ^ ((r>>1)&3).
template<bool RELU>
__global__ __launch_bounds__(512, 1) void gemm_mfma(
    const unsigned short* __restrict__ Ah, const unsigned short* __restrict__ Al,
    const unsigned short* __restrict__ Wh, const unsigned short* __restrict__ Wl,
    const float* __restrict__ bias,
    unsigned short* __restrict__ Ch, unsigned short* __restrict__ Cl) {
  __shared__ __align__(16) unsigned short smem[65536];   // 128 KB
  // layout (shorts): [buf:2][array:4][256*32]; arrays: 0=Ah 1=Al 2=Bh 3=Bl
  const int tid = threadIdx.x;
  const int lane = tid & 63;
  const int wid = tid >> 6;          // 0..7
  const int wr = wid >> 2;           // 0..1 : 128-row half
  const int wc = wid & 3;            // 0..3 : 64-col strip
  // XCD-chunked bijective swizzle (nwg % 8 == 0), bn-inner
  const int nwg = gridDim.x;         // 512
  const int hw  = blockIdx.x;
  const int logical = (hw & 7) * (nwg >> 3) + (hw >> 3);
  const int bm = logical >> 1, bn = logical & 1;
  const size_t Abase = (size_t)bm * 256 * KK;
  const size_t Bbase = (size_t)bn * 256 * KK;

  // staging: wave w stages array (w>>1), row-half (w&1)*128 ; 8 x 1KiB each
  const int sarr  = wid >> 1;
  const int rbase = (wid & 1) * 128;
  const unsigned short* gsrc = (sarr == 0) ? Ah : (sarr == 1) ? Al
                             : (sarr == 2) ? Wh : Wl;
  const size_t tb = (sarr < 2) ? Abase : Bbase;
  const int rowl = lane >> 2;                          // 0..15 in 16-row seg
  const int gch  = (lane & 3) ^ ((lane >> 3) & 3);     // pre-swizzled chunk
  const unsigned short* gbase = gsrc + tb + (size_t)(rbase + rowl) * KK + gch * 8;
  unsigned short* ldst = smem + sarr * 8192 + rbase * 32;

  // issue loads j=2p, 2p+1 (phase p's share of the 8)
  auto stage2 = [&](int buf, int kk, int p) {
#pragma unroll
    for (int j = p * 2; j < p * 2 + 2; ++j) {
      __builtin_amdgcn_global_load_lds(
          (const AS1 unsigned int*)(gbase + (size_t)(j * 16) * KK + kk),
          (AS3 unsigned int*)(ldst + buf * 32768 + j * 16 * 32),
          16, 0, 0);
    }
  };

  floatx16 acc[4][2];
#pragma unroll
  for (int i = 0; i < 4; ++i)
#pragma unroll
    for (int j = 0; j < 2; ++j)
#pragma unroll
      for (int r = 0; r < 16; ++r) acc[i][j][r] = 0.f;

  // prologue: full tile 0
#pragma unroll
  for (int p = 0; p < 4; ++p) stage2(0, 0, p);

  const int swz = (lane >> 1) & 3;
#pragma unroll
  for (int t = 0; t < 16; ++t) {
    const int cur = t & 1;
    const unsigned short* base = smem + cur * 32768;
    short8 fbh[2], fbl[2];                 // live across the 2 phases of a ks
#pragma unroll
    for (int p = 0; p < 4; ++p) {
      const int ks = p >> 1, h = p & 1;
      const int ch = ks * 2 + (lane >> 5);             // wanted 16B chunk
      const int sw = (ch ^ swz) * 8;
      short8 fah[2], fal[2];

      if (p == 0) {
        // tile-boundary: issue first prefetch pair, count-wait tile t, barrier
        if (t < 15) {
          stage2(cur ^ 1, (t + 1) * GK, 0);
          asm volatile("s_waitcnt vmcnt(2)" ::: "memory");  // 8 tile-t loads done
        } else {
          asm volatile("s_waitcnt vmcnt(0)" ::: "memory");
        }
        __builtin_amdgcn_s_barrier();                  // tile t visible to all
        __builtin_amdgcn_sched_barrier(0);
      }

      // ds-reads for THIS phase's MFMA cluster
#pragma unroll
      for (int q = 0; q < 2; ++q) {
        int row = wr * 128 + (h * 2 + q) * 32 + (lane & 31);
        fah[q] = *(const short8*)(base + row * 32 + sw);
        fal[q] = *(const short8*)(base + 8192 + row * 32 + sw);
      }
      if (h == 0) {
#pragma unroll
        for (int si = 0; si < 2; ++si) {
          int col = wc * 64 + si * 32 + (lane & 31);
          fbh[si] = *(const short8*)(base + 16384 + col * 32 + sw);
          fbl[si] = *(const short8*)(base + 24576 + col * 32 + sw);
        }
      }

      if (p > 0) {
        if (t < 15) stage2(cur ^ 1, (t + 1) * GK, p);  // next 2 prefetch loads
        __builtin_amdgcn_sched_barrier(0);
        __builtin_amdgcn_s_barrier();                  // reads fly under barrier
        __builtin_amdgcn_sched_barrier(0);
      }

      __builtin_amdgcn_s_setprio(1);
#pragma unroll
      for (int q = 0; q < 2; ++q)
#pragma unroll
        for (int si = 0; si < 2; ++si) {
          const int ri = h * 2 + q;
          acc[ri][si] = __builtin_amdgcn_mfma_f32_32x32x16_bf16(fah[q], fbh[si], acc[ri][si], 0, 0, 0);
          acc[ri][si] = __builtin_amdgcn_mfma_f32_32x32x16_bf16(fah[q], fbl[si], acc[ri][si], 0, 0, 0);
          acc[ri][si] = __builtin_amdgcn_mfma_f32_32x32x16_bf16(fal[q], fbh[si], acc[ri][si], 0, 0, 0);
        }
      __builtin_amdgcn_s_setprio(0);
      __builtin_amdgcn_sched_barrier(0);
      __builtin_amdgcn_s_barrier();                    // end-phase
    }
  }

  // ---- chunked coalesced epilogue: 4 passes of [64][256] packed (h|l<<16) ----
  float bv[2];
#pragma unroll
  for (int si = 0; si < 2; ++si)
    bv[si] = bias[bn * 256 + wc * 64 + si * 32 + (lane & 31)];

  unsigned* lds32 = (unsigned*)smem;                   // [64][256] = 64 KB
#pragma unroll
  for (int ri = 0; ri < 4; ++ri) {
    __syncthreads();                                   // lds32 free for reuse
#pragma unroll
    for (int si = 0; si < 2; ++si) {
      int lcol = wc * 64 + si * 32 + (lane & 31);
#pragma unroll
      for (int r = 0; r < 16; ++r) {
        int frow = (r & 3) + 8 * (r >> 2) + 4 * (lane >> 5);
        float v = acc[ri][si][r] + bv[si];
        if (RELU) v = fmaxf(v, 0.f);
        unsigned short h = bf16_rn(v);
        unsigned short lo = bf16_rn(v - bf16_to_f32(h));
        lds32[(wr * 32 + frow) * 256 + lcol] = (unsigned)h | ((unsigned)lo << 16);
      }
    }
    __syncthreads();
#pragma unroll
    for (int p = 0; p < 8; ++p) {
      int c = tid + p * 512;                           // 0..4095 uint4-chunks
      int lrow = c >> 6;
      int cc = (c & 63) * 4;
      uint4 d = *(const uint4*)&lds32[lrow * 256 + cc];
      ushort4 hv, lv;
      hv.x = (unsigned short)(d.x); lv.x = (unsigned short)(d.x >> 16);
      hv.y = (unsigned short)(d.y); lv.y = (unsigned short)(d.y >> 16);
      hv.z = (unsigned short)(d.z); lv.z = (unsigned short)(d.z >> 16);
      hv.w = (unsigned short)(d.w); lv.w = (unsigned short)(d.w >> 16);
      int grow = bm * 256 + (lrow >> 5) * 128 + ri * 32 + (lrow & 31);
      size_t gi = (size_t)grow * NN + bn * 256 + cc;
      *(ushort4*)&Ch[gi] = hv;                         // full-line bursts
      *(ushort4*)&Cl[gi] = lv;
    }
  }
}

// H2+H3 fused: mu = mh @ wgh^T + wgb (1-term bf16), then write only the
// y-selected class columns: z[b,e] = mu[b, y_b*16+e]. Counted-vmcnt pipeline.
// XCD-chunked swizzle, bn-inner (A-panel fetched once, not x2).
__global__ __launch_bounds__(256, 2) void gemm_muz(
    const unsigned short* __restrict__ Ahm, const unsigned short* __restrict__ Wh,
    const float* __restrict__ bias, const float* __restrict__ y_in,
    float* __restrict__ z_out) {
  __shared__ __align__(16) unsigned short smem[16384];   // 32 KB
  unsigned short* sA = smem;             // [2][128][32]
  unsigned short* sB = smem + 8192;
  const int tid = threadIdx.x;
  const int lane = tid & 63;
  const int wid = tid >> 6;
  const int wr = wid >> 1;
  const int wc = wid & 1;
  const int nwg = gridDim.x;
  const int hw  = blockIdx.x;
  const int logical = (hw & 7) * (nwg >> 3) + (hw >> 3);
  const int bm = logical >> 1, bn = logical & 1;
  const size_t Abase = (size_t)bm * GM * KK;
  const size_t Bbase = (size_t)bn * GN * KK;

  const unsigned short* gsrc = (wid < 2) ? Ahm : Wh;
  const size_t tb = (wid < 2) ? Abase : Bbase;
  unsigned short* ldst = (wid < 2) ? sA : sB;
  const int rbase = (wid & 1) * 64;
  const int rowl = lane >> 2;
  const int gch  = (lane & 3) ^ ((lane >> 3) & 3);
  const unsigned short* gbase = gsrc + tb + (size_t)rowl * KK + gch * 8;

  auto stage = [&](int buf, int kk) {
#pragma unroll
    for (int j = 0; j < 4; ++j) {
      const int r0 = rbase + j * 16;
      __builtin_amdgcn_global_load_lds(
          (const AS1 unsigned int*)(gbase + (size_t)r0 * KK + kk),
          (AS3 unsigned int*)(ldst + buf * 4096 + r0 * GK),
          16, 0, 0);
    }
  };

  floatx16 acc[2][2];
#pragma unroll
  for (int i = 0; i < 2; ++i)
#pragma unroll
    for (int j = 0; j < 2; ++j)
#pragma unroll
      for (int r = 0; r < 16; ++r) acc[i][j][r] = 0.f;

  stage(0, 0);

  const int swz = (lane >> 1) & 3;
  int cur = 0;
#pragma unroll
  for (int k0 = 0; k0 < KK; k0 += GK) {
    if (k0 + GK < KK) {
      stage(cur ^ 1, k0 + GK);
      asm volatile("s_waitcnt vmcnt(4)" ::: "memory");
    } else {
      asm volatile("s_waitcnt vmcnt(0)" ::: "memory");
    }
    __builtin_amdgcn_s_barrier();
    __builtin_amdgcn_sched_barrier(0);

    const unsigned short* pA = sA + cur * 4096;
    const unsigned short* pB = sB + cur * 4096;
#pragma unroll
    for (int ks = 0; ks < 2; ++ks) {
      const int ch = ks * 2 + (lane >> 5);
      const int sw = (ch ^ swz) * 8;
      short8 fa[2], fb[2];
#pragma unroll
      for (int ri = 0; ri < 2; ++ri) {
        int row = wr * 64 + ri * 32 + (lane & 31);
        fa[ri] = *(const short8*)(pA + row * GK + sw);
      }
#pragma unroll
      for (int si = 0; si < 2; ++si) {
        int col = wc * 64 + si * 32 + (lane & 31);
        fb[si] = *(const short8*)(pB + col * GK + sw);
      }
#pragma unroll
      for (int ri = 0; ri < 2; ++ri)
#pragma unroll
        for (int si = 0; si < 2; ++si)
          acc[ri][si] = __builtin_amdgcn_mfma_f32_32x32x16_bf16(fa[ri], fb[si], acc[ri][si], 0, 0, 0);
    }
    __builtin_amdgcn_sched_barrier(0);
    __builtin_amdgcn_s_barrier();
    cur ^= 1;
  }

  // epilogue: select-write. col -> class k=col>>4, latent e=col&15.
  int colv[2]; float bv[2];
#pragma unroll
  for (int si = 0; si < 2; ++si) {
    colv[si] = bn * GN + wc * 64 + si * 32 + (lane & 31);
    bv[si] = bias[colv[si]];
  }
#pragma unroll
  for (int ri = 0; ri < 2; ++ri)
#pragma unroll
    for (int r = 0; r < 16; ++r) {
      int row = bm * GM + wr * 64 + ri * 32 + (r & 3) + 8 * (r >> 2) + 4 * (lane >> 5);
      int yv = (int)y_in[row];
#pragma unroll
      for (int si = 0; si < 2; ++si) {
        if ((colv[si] >> 4) == yv)
          z_out[(size_t)row * 16 + (colv[si] & 15)] = acc[ri][si][r] + bv[si];
      }
    }
}

// H1: logits[65536,16] = (mh+ml) @ (wch+wcl)^T + bc via 3-term 16x16x32 MFMA,
// then per-row argmax -> y. A: row=lane&15, k=(lane>>4)*8+j; B symmetric;
// C/D: col=lane&15, row=(lane>>4)*4+reg  [m89/m91 verified].
__global__ __launch_bounds__(256) void logits_kernel(
    const unsigned short* __restrict__ mh, const unsigned short* __restrict__ ml,
    const unsigned short* __restrict__ wch, const unsigned short* __restrict__ wcl,
    const float* __restrict__ bc, float* __restrict__ y_out) {
  __shared__ unsigned short smh[64][LDT], sml[64][LDT];
  __shared__ float slog[64][17];
  const int tid = threadIdx.x;
  const int lane = tid & 63;
  const int wid = tid >> 6;            // wave -> rows wid*16..+16
  const size_t row0 = (size_t)blockIdx.x * 64;
  const int fr = lane & 15;
  const int fq = lane >> 4;

  floatx4 acc = {0.f, 0.f, 0.f, 0.f};
  const unsigned short* bh = wch + fr * 512 + fq * 8;   // Wc-split: 32 KB, L1/L2-hot
  const unsigned short* bl = wcl + fr * 512 + fq * 8;

  for (int k0 = 0; k0 < 512; k0 += 32) {
    {
      int row = tid >> 2, cc = (tid & 3) * 8;          // 256 chunks = 64 rows x 4
      size_t g = (row0 + row) * 512 + k0 + cc;
      *(short8*)&smh[row][cc] = *(const short8*)(mh + g);
      *(short8*)&sml[row][cc] = *(const short8*)(ml + g);
    }
    __syncthreads();
    short8 ah = *(const short8*)&smh[wid * 16 + fr][fq * 8];
    short8 al = *(const short8*)&sml[wid * 16 + fr][fq * 8];
    short8 fbh = *(const short8*)(bh + k0);
    short8 fbl = *(const short8*)(bl + k0);
    acc = __builtin_amdgcn_mfma_f32_16x16x32_bf16(ah, fbh, acc, 0, 0, 0);
    acc = __builtin_amdgcn_mfma_f32_16x16x32_bf16(ah, fbl, acc, 0, 0, 0);
    acc = __builtin_amdgcn_mfma_f32_16x16x32_bf16(al, fbh, acc, 0, 0, 0);
    __syncthreads();
  }
#pragma unroll
  for (int r = 0; r < 4; ++r)
    slog[wid * 16 + fq * 4 + r][fr] = acc[r] + bc[fr];
  __syncthreads();
  if (tid < 64) {
    float best = slog[tid][0];
    int bi = 0;
#pragma unroll
    for (int j = 1; j < 16; ++j) {     // strict >: first-max, matches np argmax
      float v = slog[tid][j];
      if (v > best) { best = v; bi = j; }
    }
    y_out[row0 + tid] = (float)bi;
  }
}

// prep: Wg[16,32,512] mu-rows -> wgh[256,512] bf16; wgb[col]=bg[col/16,col%16]
__global__ __launch_bounds__(256) void prep_wg(
    const float* __restrict__ Wg, const float* __restrict__ bg,
    unsigned short* __restrict__ wgh, float* __restrict__ wgb) {
  int gid = blockIdx.x * 256 + threadIdx.x;    // 32768 threads x 4 elems
  if (gid >= 32768) return;
  int r = gid >> 7;
  int c4 = (gid & 127) * 4;
  int k = r >> 4, e = r & 15;
  float4 v = *(const float4*)(Wg + ((size_t)k * 32 + e) * 512 + c4);
  ushort4 h;
  h.x = bf16_rn(v.x); h.y = bf16_rn(v.y); h.z = bf16_rn(v.z); h.w = bf16_rn(v.w);
  *(ushort4*)(wgh + (size_t)r * 512 + c4) = h;
  if (c4 == 0) wgb[r] = bg[k * 32 + e];
}

extern "C" void kernel_launch(void* const* d_in, const int* in_sizes, int n_in,
                              void* d_out, int out_size, void* d_ws, size_t ws_size,
                              hipStream_t stream) {
  const float* x  = (const float*)d_in[0];
  const float* W0 = (const float*)d_in[1];
  const float* b0 = (const float*)d_in[2];
  const float* W1 = (const float*)d_in[3];
  const float* b1 = (const float*)d_in[4];
  const float* W2 = (const float*)d_in[5];
  const float* b2 = (const float*)d_in[6];
  const float* Wc = (const float*)d_in[7];
  const float* bc = (const float*)d_in[8];
  const float* Wg = (const float*)d_in[9];
  const float* bg = (const float*)d_in[10];

  const size_t NEL = (size_t)MM * KK;
  unsigned short* Ah = (unsigned short*)d_ws;           // 64 MiB each
  unsigned short* Al = Ah + NEL;
  unsigned short* Bh = Al + NEL;
  unsigned short* Bl = Bh + NEL;
  // After GEMM3 (out: Bh/Bl = m-split), Ah/Al regions are free:
  unsigned short* wch = Al;                             // 16 KB
  unsigned short* wcl = Al + 8192;                      // 16 KB
  unsigned short* wgh = Al + 16384;                     // 256 KB
  float* wgb = (float*)(Al + 16384 + 131072);           // 1 KB

  // W-layer splits staged in d_out (3 MiB < 4.5 MiB); dead once GEMM3 done,
  // then overwritten by z (gemm_muz).
  unsigned short* w0h = (unsigned short*)d_out;
  unsigned short* w0l = w0h + 262144;
  unsigned short* w1h = w0l + 262144;
  unsigned short* w1l = w1h + 262144;
  unsigned short* w2h = w1l + 262144;
  unsigned short* w2l = w2h + 262144;

  float* z_out = (float*)d_out;
  float* y_out = z_out + (size_t)MM * 16;               // at +4 MiB, clear of w-splits

  split_kernel<<<(int)(NEL / 4 / 256), 256, 0, stream>>>(x, Ah, Al, (int)(NEL / 4));
  split_kernel<<<256, 256, 0, stream>>>(W0, w0h, w0l, 65536);
  split_kernel<<<256, 256, 0, stream>>>(W1, w1h, w1l, 65536);
  split_kernel<<<256, 256, 0, stream>>>(W2, w2h, w2l, 65536);

  const int ngrid = (MM / 256) * (NN / 256);            // 512, %8==0
  gemm_mfma<true ><<<ngrid, 512, 0, stream>>>(Ah, Al, w0h, w0l, b0, Bh, Bl);
  gemm_mfma<true ><<<ngrid, 512, 0, stream>>>(Bh, Bl, w1h, w1l, b1, Ah, Al);
  gemm_mfma<false><<<ngrid, 512, 0, stream>>>(Ah, Al, w2h, w2l, b2, Bh, Bl);

  // head preps (Ah/Al free from here)
  split_kernel<<<8, 256, 0, stream>>>(Wc, wch, wcl, 2048);
  prep_wg<<<128, 256, 0, stream>>>(Wg, bg, wgh, wgb);

  logits_kernel<<<MM / 64, 256, 0, stream>>>(Bh, Bl, wch, wcl, bc, y_out);
  gemm_muz<<<(MM / GM) * 2, 256, 0, stream>>>(Bh, wgh, wgb, y_out, z_out);
}

// Round 8
// 587.036 us; speedup vs baseline: 1.1732x; 1.0485x over previous
//
#include <hip/hip_runtime.h>
#include <hip/hip_bf16.h>

typedef __attribute__((ext_vector_type(8))) short short8;
typedef __attribute__((ext_vector_type(16))) float floatx16;
typedef __attribute__((ext_vector_type(4))) float floatx4;

#define AS1 __attribute__((address_space(1)))
#define AS3 __attribute__((address_space(3)))

constexpr int MM = 65536;   // batch
constexpr int KK = 512;     // inner dim
constexpr int NN = 512;     // out dim per layer

#define GK 32
#define LDT 40   // logits kernel LDS row stride (shorts)

// round-to-nearest-even fp32 -> bf16 (bit-level, finite inputs)
__device__ __forceinline__ unsigned short bf16_rn(float v) {
  unsigned u = __float_as_uint(v);
  return (unsigned short)((u + 0x7FFFu + ((u >> 16) & 1u)) >> 16);
}
__device__ __forceinline__ float bf16_to_f32(unsigned short h) {
  return __uint_as_float((unsigned)h << 16);
}

// src fp32 -> (hi, lo) bf16 arrays. n4 = element count / 4. (weights only now)
__global__ __launch_bounds__(256) void split_kernel(
    const float* __restrict__ src, unsigned short* __restrict__ h,
    unsigned short* __restrict__ l, int n4) {
  int i = blockIdx.x * 256 + threadIdx.x;
  if (i >= n4) return;
  float4 v = ((const float4*)src)[i];
  ushort4 hv, lv;
  hv.x = bf16_rn(v.x); lv.x = bf16_rn(v.x - bf16_to_f32(hv.x));
  hv.y = bf16_rn(v.y); lv.y = bf16_rn(v.y - bf16_to_f32(hv.y));
  hv.z = bf16_rn(v.z); lv.z = bf16_rn(v.z - bf16_to_f32(hv.z));
  hv.w = bf16_rn(v.w); lv.w = bf16_rn(v.w - bf16_to_f32(hv.w));
  ((ushort4*)h)[i] = hv;
  ((ushort4*)l)[i] = lv;
}

// ---------------------------------------------------------------------------
// GEMM layers 2,3 (A already split): R9 4-phase interleave, unchanged.
// LDS layout (shorts): addr = buf*32768 + arr*8192 + row*32; arr 0=Ah 1=Al
// 2=Bh 3=Bl. Swizzle: phys chunk p of row r holds logical p ^ ((r>>1)&3).
// ---------------------------------------------------------------------------
template<bool RELU>
__global__ __launch_bounds__(512, 1) void gemm_mfma(
    const unsigned short* __restrict__ Ah, const unsigned short* __restrict__ Al,
    const unsigned short* __restrict__ Wh, const unsigned short* __restrict__ Wl,
    const float* __restrict__ bias,
    unsigned short* __restrict__ Ch, unsigned short* __restrict__ Cl) {
  __shared__ __align__(16) unsigned short smem[65536];   // 128 KB
  const int tid = threadIdx.x;
  const int lane = tid & 63;
  const int wid = tid >> 6;          // 0..7
  const int wr = wid >> 2;           // 0..1 : 128-row half
  const int wc = wid & 3;            // 0..3 : 64-col strip
  const int nwg = gridDim.x;         // 512
  const int hw  = blockIdx.x;
  const int logical = (hw & 7) * (nwg >> 3) + (hw >> 3);
  const int bm = logical >> 1, bn = logical & 1;
  const size_t Abase = (size_t)bm * 256 * KK;
  const size_t Bbase = (size_t)bn * 256 * KK;

  const int sarr  = wid >> 1;
  const int rbase = (wid & 1) * 128;
  const unsigned short* gsrc = (sarr == 0) ? Ah : (sarr == 1) ? Al
                             : (sarr == 2) ? Wh : Wl;
  const size_t tb = (sarr < 2) ? Abase : Bbase;
  const int rowl = lane >> 2;
  const int gch  = (lane & 3) ^ ((lane >> 3) & 3);
  const unsigned short* gbase = gsrc + tb + (size_t)(rbase + rowl) * KK + gch * 8;
  unsigned short* ldst = smem + sarr * 8192 + rbase * 32;

  auto stage2 = [&](int buf, int kk, int p) {
#pragma unroll
    for (int j = p * 2; j < p * 2 + 2; ++j) {
      __builtin_amdgcn_global_load_lds(
          (const AS1 unsigned int*)(gbase + (size_t)(j * 16) * KK + kk),
          (AS3 unsigned int*)(ldst + buf * 32768 + j * 16 * 32),
          16, 0, 0);
    }
  };

  floatx16 acc[4][2];
#pragma unroll
  for (int i = 0; i < 4; ++i)
#pragma unroll
    for (int j = 0; j < 2; ++j)
#pragma unroll
      for (int r = 0; r < 16; ++r) acc[i][j][r] = 0.f;

#pragma unroll
  for (int p = 0; p < 4; ++p) stage2(0, 0, p);

  const int swz = (lane >> 1) & 3;
#pragma unroll
  for (int t = 0; t < 16; ++t) {
    const int cur = t & 1;
    const unsigned short* base = smem + cur * 32768;
    short8 fbh[2], fbl[2];
#pragma unroll
    for (int p = 0; p < 4; ++p) {
      const int ks = p >> 1, h = p & 1;
      const int ch = ks * 2 + (lane >> 5);
      const int sw = (ch ^ swz) * 8;
      short8 fah[2], fal[2];

      if (p == 0) {
        if (t < 15) {
          stage2(cur ^ 1, (t + 1) * GK, 0);
          asm volatile("s_waitcnt vmcnt(2)" ::: "memory");
        } else {
          asm volatile("s_waitcnt vmcnt(0)" ::: "memory");
        }
        __builtin_amdgcn_s_barrier();
        __builtin_amdgcn_sched_barrier(0);
      }

#pragma unroll
      for (int q = 0; q < 2; ++q) {
        int row = wr * 128 + (h * 2 + q) * 32 + (lane & 31);
        fah[q] = *(const short8*)(base + row * 32 + sw);
        fal[q] = *(const short8*)(base + 8192 + row * 32 + sw);
      }
      if (h == 0) {
#pragma unroll
        for (int si = 0; si < 2; ++si) {
          int col = wc * 64 + si * 32 + (lane & 31);
          fbh[si] = *(const short8*)(base + 16384 + col * 32 + sw);
          fbl[si] = *(const short8*)(base + 24576 + col * 32 + sw);
        }
      }

      if (p > 0) {
        if (t < 15) stage2(cur ^ 1, (t + 1) * GK, p);
        __builtin_amdgcn_sched_barrier(0);
        __builtin_amdgcn_s_barrier();
        __builtin_amdgcn_sched_barrier(0);
      }

      __builtin_amdgcn_s_setprio(1);
#pragma unroll
      for (int q = 0; q < 2; ++q)
#pragma unroll
        for (int si = 0; si < 2; ++si) {
          const int ri = h * 2 + q;
          acc[ri][si] = __builtin_amdgcn_mfma_f32_32x32x16_bf16(fah[q], fbh[si], acc[ri][si], 0, 0, 0);
          acc[ri][si] = __builtin_amdgcn_mfma_f32_32x32x16_bf16(fah[q], fbl[si], acc[ri][si], 0, 0, 0);
          acc[ri][si] = __builtin_amdgcn_mfma_f32_32x32x16_bf16(fal[q], fbh[si], acc[ri][si], 0, 0, 0);
        }
      __builtin_amdgcn_s_setprio(0);
      __builtin_amdgcn_sched_barrier(0);
      __builtin_amdgcn_s_barrier();
    }
  }

  // chunked coalesced epilogue (R8-verified)
  float bv[2];
#pragma unroll
  for (int si = 0; si < 2; ++si)
    bv[si] = bias[bn * 256 + wc * 64 + si * 32 + (lane & 31)];

  unsigned* lds32 = (unsigned*)smem;
#pragma unroll
  for (int ri = 0; ri < 4; ++ri) {
    __syncthreads();
#pragma unroll
    for (int si = 0; si < 2; ++si) {
      int lcol = wc * 64 + si * 32 + (lane & 31);
#pragma unroll
      for (int r = 0; r < 16; ++r) {
        int frow = (r & 3) + 8 * (r >> 2) + 4 * (lane >> 5);
        float v = acc[ri][si][r] + bv[si];
        if (RELU) v = fmaxf(v, 0.f);
        unsigned short h = bf16_rn(v);
        unsigned short lo = bf16_rn(v - bf16_to_f32(h));
        lds32[(wr * 32 + frow) * 256 + lcol] = (unsigned)h | ((unsigned)lo << 16);
      }
    }
    __syncthreads();
#pragma unroll
    for (int p = 0; p < 8; ++p) {
      int c = tid + p * 512;
      int lrow = c >> 6;
      int cc = (c & 63) * 4;
      uint4 d = *(const uint4*)&lds32[lrow * 256 + cc];
      ushort4 hv, lv;
      hv.x = (unsigned short)(d.x); lv.x = (unsigned short)(d.x >> 16);
      hv.y = (unsigned short)(d.y); lv.y = (unsigned short)(d.y >> 16);
      hv.z = (unsigned short)(d.z); lv.z = (unsigned short)(d.z >> 16);
      hv.w = (unsigned short)(d.w); lv.w = (unsigned short)(d.w >> 16);
      int grow = bm * 256 + (lrow >> 5) * 128 + ri * 32 + (lrow & 31);
      size_t gi = (size_t)grow * NN + bn * 256 + cc;
      *(ushort4*)&Ch[gi] = hv;
      *(ushort4*)&Cl[gi] = lv;
    }
  }
}

// ---------------------------------------------------------------------------
// GEMM layer 1: A = x (fp32) split ON THE FLY in staging (kills split_x).
// B (W-split) via global_load_lds as before. Per wave per tile: 4 B-gloads
// + 4 A f32 dwordx4 issued at p0; drained vmcnt(0) after p3's MFMA, convert
// + swizzled ds_write_b64, lgkmcnt(0), publish barrier. RELU always.
// ---------------------------------------------------------------------------
__global__ __launch_bounds__(512, 1) void gemm_x(
    const float* __restrict__ X,
    const unsigned short* __restrict__ Wh, const unsigned short* __restrict__ Wl,
    const float* __restrict__ bias,
    unsigned short* __restrict__ Ch, unsigned short* __restrict__ Cl) {
  __shared__ __align__(16) unsigned short smem[65536];   // 128 KB, same layout
  const int tid = threadIdx.x;
  const int lane = tid & 63;
  const int wid = tid >> 6;
  const int wr = wid >> 2;
  const int wc = wid & 3;
  const int nwg = gridDim.x;
  const int hw  = blockIdx.x;
  const int logical = (hw & 7) * (nwg >> 3) + (hw >> 3);
  const int bm = logical >> 1, bn = logical & 1;

  // B staging: wave w -> array (w>>2): 0=Wh, 1=Wl; rows (w&3)*64 .. +64
  const int barr = wid >> 2;
  const int brb  = (wid & 3) * 64;
  const int rowl = lane >> 2;
  const int gch  = (lane & 3) ^ ((lane >> 3) & 3);
  const unsigned short* gbB = (barr ? Wl : Wh) + (size_t)bn * 256 * KK
                            + (size_t)(brb + rowl) * KK + gch * 8;
  unsigned short* ldB = smem + (2 + barr) * 8192 + brb * 32;

  auto stageB = [&](int buf, int kk) {
#pragma unroll
    for (int j = 0; j < 4; ++j) {
      __builtin_amdgcn_global_load_lds(
          (const AS1 unsigned int*)(gbB + (size_t)(j * 16) * KK + kk),
          (AS3 unsigned int*)(ldB + buf * 32768 + j * 16 * 32),
          16, 0, 0);
    }
  };

  // A f32 loads: wave w -> rows w*32 .. +32; lane: arow=lane>>3 (8 rows/load),
  // akc=lane&7 (4-float chunk -> k = akc*4)
  const int arow = lane >> 3;
  const int akc  = lane & 7;
  const float* gx = X + ((size_t)(bm * 256 + wid * 32) + arow) * KK + akc * 4;
  auto loadA = [&](int kk, float4* av) {
#pragma unroll
    for (int j = 0; j < 4; ++j)
      av[j] = *(const float4*)(gx + (size_t)(j * 8) * KK + kk);
  };
  // phys chunk for A write: (akc>>1) ^ ((arow>>1)&3)  [row>>1&3 == arow>>1&3]
  const int apc = ((akc >> 1) ^ ((arow >> 1) & 3));
  const int aoff = (wid * 32 + arow) * 32 + apc * 8 + (akc & 1) * 4;
  auto writeA = [&](int buf, const float4* av) {
#pragma unroll
    for (int j = 0; j < 4; ++j) {
      ushort4 hv, lv;
      hv.x = bf16_rn(av[j].x); lv.x = bf16_rn(av[j].x - bf16_to_f32(hv.x));
      hv.y = bf16_rn(av[j].y); lv.y = bf16_rn(av[j].y - bf16_to_f32(hv.y));
      hv.z = bf16_rn(av[j].z); lv.z = bf16_rn(av[j].z - bf16_to_f32(hv.z));
      hv.w = bf16_rn(av[j].w); lv.w = bf16_rn(av[j].w - bf16_to_f32(hv.w));
      int o = buf * 32768 + aoff + j * 8 * 32;     // +8 rows per j
      *(ushort4*)(smem + o) = hv;                  // sAh
      *(ushort4*)(smem + 8192 + o) = lv;           // sAl
    }
  };

  floatx16 acc[4][2];
#pragma unroll
  for (int i = 0; i < 4; ++i)
#pragma unroll
    for (int j = 0; j < 2; ++j)
#pragma unroll
      for (int r = 0; r < 16; ++r) acc[i][j][r] = 0.f;

  // prologue: tile 0 fully staged + published
  {
    float4 av0[4];
    stageB(0, 0);
    loadA(0, av0);
    asm volatile("s_waitcnt vmcnt(0)" ::: "memory");
    writeA(0, av0);
    asm volatile("s_waitcnt lgkmcnt(0)" ::: "memory");
    __builtin_amdgcn_s_barrier();
  }

  const int swz = (lane >> 1) & 3;
#pragma unroll
  for (int t = 0; t < 16; ++t) {
    const int cur = t & 1;
    const unsigned short* base = smem + cur * 32768;
    short8 fbh[2], fbl[2];
    float4 av[4];
#pragma unroll
    for (int p = 0; p < 4; ++p) {
      const int ks = p >> 1, h = p & 1;
      const int ch = ks * 2 + (lane >> 5);
      const int sw = (ch ^ swz) * 8;
      short8 fah[2], fal[2];

      if (p == 0 && t < 15) {
        stageB(cur ^ 1, (t + 1) * GK);
        loadA((t + 1) * GK, av);
      }

#pragma unroll
      for (int q = 0; q < 2; ++q) {
        int row = wr * 128 + (h * 2 + q) * 32 + (lane & 31);
        fah[q] = *(const short8*)(base + row * 32 + sw);
        fal[q] = *(const short8*)(base + 8192 + row * 32 + sw);
      }
      if (h == 0) {
#pragma unroll
        for (int si = 0; si < 2; ++si) {
          int col = wc * 64 + si * 32 + (lane & 31);
          fbh[si] = *(const short8*)(base + 16384 + col * 32 + sw);
          fbl[si] = *(const short8*)(base + 24576 + col * 32 + sw);
        }
      }

      __builtin_amdgcn_s_setprio(1);
#pragma unroll
      for (int q = 0; q < 2; ++q)
#pragma unroll
        for (int si = 0; si < 2; ++si) {
          const int ri = h * 2 + q;
          acc[ri][si] = __builtin_amdgcn_mfma_f32_32x32x16_bf16(fah[q], fbh[si], acc[ri][si], 0, 0, 0);
          acc[ri][si] = __builtin_amdgcn_mfma_f32_32x32x16_bf16(fah[q], fbl[si], acc[ri][si], 0, 0, 0);
          acc[ri][si] = __builtin_amdgcn_mfma_f32_32x32x16_bf16(fal[q], fbh[si], acc[ri][si], 0, 0, 0);
        }
      __builtin_amdgcn_s_setprio(0);
      __builtin_amdgcn_sched_barrier(0);

      if (p == 3) {
        if (t < 15) {
          asm volatile("s_waitcnt vmcnt(0)" ::: "memory");   // B gloads + A f32 done
          writeA(cur ^ 1, av);
        }
        asm volatile("s_waitcnt lgkmcnt(0)" ::: "memory");
        __builtin_amdgcn_s_barrier();                        // publish tile t+1
      } else {
        __builtin_amdgcn_s_barrier();
      }
      __builtin_amdgcn_sched_barrier(0);
    }
  }

  // epilogue: RELU + split, chunked coalesced (identical to gemm_mfma<true>)
  float bv[2];
#pragma unroll
  for (int si = 0; si < 2; ++si)
    bv[si] = bias[bn * 256 + wc * 64 + si * 32 + (lane & 31)];

  unsigned* lds32 = (unsigned*)smem;
#pragma unroll
  for (int ri = 0; ri < 4; ++ri) {
    __syncthreads();
#pragma unroll
    for (int si = 0; si < 2; ++si) {
      int lcol = wc * 64 + si * 32 + (lane & 31);
#pragma unroll
      for (int r = 0; r < 16; ++r) {
        int frow = (r & 3) + 8 * (r >> 2) + 4 * (lane >> 5);
        float v = fmaxf(acc[ri][si][r] + bv[si], 0.f);
        unsigned short h = bf16_rn(v);
        unsigned short lo = bf16_rn(v - bf16_to_f32(h));
        lds32[(wr * 32 + frow) * 256 + lcol] = (unsigned)h | ((unsigned)lo << 16);
      }
    }
    __syncthreads();
#pragma unroll
    for (int p = 0; p < 8; ++p) {
      int c = tid + p * 512;
      int lrow = c >> 6;
      int cc = (c & 63) * 4;
      uint4 d = *(const uint4*)&lds32[lrow * 256 + cc];
      ushort4 hv, lv;
      hv.x = (unsigned short)(d.x); lv.x = (unsigned short)(d.x >> 16);
      hv.y = (unsigned short)(d.y); lv.y = (unsigned short)(d.y >> 16);
      hv.z = (unsigned short)(d.z); lv.z = (unsigned short)(d.z >> 16);
      hv.w = (unsigned short)(d.w); lv.w = (unsigned short)(d.w >> 16);
      int grow = bm * 256 + (lrow >> 5) * 128 + ri * 32 + (lrow & 31);
      size_t gi = (size_t)grow * NN + bn * 256 + cc;
      *(ushort4*)&Ch[gi] = hv;
      *(ushort4*)&Cl[gi] = lv;
    }
  }
}

// ---------------------------------------------------------------------------
// H2+H3: mu = mh @ wgh^T + wgb (1-term), select-write z. R9 skeleton at
// 256xM tile covering ALL N=256 in one block (grid = MM/256 = 256 blocks).
// 1-term -> 4 MFMA/phase; 1 gload/wave/phase; vmcnt(1). LDS 64 KB.
// ---------------------------------------------------------------------------
__global__ __launch_bounds__(512) void gemm_muz(
    const unsigned short* __restrict__ Ahm, const unsigned short* __restrict__ Wh,
    const float* __restrict__ bias, const float* __restrict__ y_in,
    float* __restrict__ z_out) {
  __shared__ __align__(16) unsigned short smem[32768];   // 64 KB
  // addr = buf*16384 + arr*8192 + row*32 ; arr 0=A 1=B
  const int tid = threadIdx.x;
  const int lane = tid & 63;
  const int wid = tid >> 6;
  const int wr = wid >> 2;
  const int wc = wid & 3;
  const int bm = blockIdx.x;

  const int sarr = (wid < 4) ? 0 : 1;
  const int rb   = (wid & 3) * 64;
  const unsigned short* gsrc = sarr ? Wh : (Ahm + (size_t)bm * 256 * KK);
  const int rowl = lane >> 2;
  const int gch  = (lane & 3) ^ ((lane >> 3) & 3);
  const unsigned short* gbase = gsrc + (size_t)(rb + rowl) * KK + gch * 8;
  unsigned short* ldst = smem + sarr * 8192 + rb * 32;

  auto stage1 = [&](int buf, int kk, int j) {
    __builtin_amdgcn_global_load_lds(
        (const AS1 unsigned int*)(gbase + (size_t)(j * 16) * KK + kk),
        (AS3 unsigned int*)(ldst + buf * 16384 + j * 16 * 32),
        16, 0, 0);
  };

  floatx16 acc[4][2];
#pragma unroll
  for (int i = 0; i < 4; ++i)
#pragma unroll
    for (int j = 0; j < 2; ++j)
#pragma unroll
      for (int r = 0; r < 16; ++r) acc[i][j][r] = 0.f;

#pragma unroll
  for (int j = 0; j < 4; ++j) stage1(0, 0, j);

  const int swz = (lane >> 1) & 3;
#pragma unroll
  for (int t = 0; t < 16; ++t) {
    const int cur = t & 1;
    const unsigned short* base = smem + cur * 16384;
    short8 fb[2];
#pragma unroll
    for (int p = 0; p < 4; ++p) {
      const int ks = p >> 1, h = p & 1;
      const int ch = ks * 2 + (lane >> 5);
      const int sw = (ch ^ swz) * 8;
      short8 fa[2];

      if (p == 0) {
        if (t < 15) {
          stage1(cur ^ 1, (t + 1) * GK, 0);
          asm volatile("s_waitcnt vmcnt(1)" ::: "memory");
        } else {
          asm volatile("s_waitcnt vmcnt(0)" ::: "memory");
        }
        __builtin_amdgcn_s_barrier();
        __builtin_amdgcn_sched_barrier(0);
      }

#pragma unroll
      for (int q = 0; q < 2; ++q) {
        int row = wr * 128 + (h * 2 + q) * 32 + (lane & 31);
        fa[q] = *(const short8*)(base + row * 32 + sw);
      }
      if (h == 0) {
#pragma unroll
        for (int si = 0; si < 2; ++si) {
          int col = wc * 64 + si * 32 + (lane & 31);
          fb[si] = *(const short8*)(base + 8192 + col * 32 + sw);
        }
      }

      if (p > 0) {
        if (t < 15) stage1(cur ^ 1, (t + 1) * GK, p);
        __builtin_amdgcn_sched_barrier(0);
        __builtin_amdgcn_s_barrier();
        __builtin_amdgcn_sched_barrier(0);
      }

      __builtin_amdgcn_s_setprio(1);
#pragma unroll
      for (int q = 0; q < 2; ++q)
#pragma unroll
        for (int si = 0; si < 2; ++si)
          acc[h * 2 + q][si] = __builtin_amdgcn_mfma_f32_32x32x16_bf16(fa[q], fb[si], acc[h * 2 + q][si], 0, 0, 0);
      __builtin_amdgcn_s_setprio(0);
      __builtin_amdgcn_sched_barrier(0);
      __builtin_amdgcn_s_barrier();
    }
  }

  // select-epilogue: col in 0..255; class = col>>4, latent e = col&15
  int colv[2]; float bv[2];
#pragma unroll
  for (int si = 0; si < 2; ++si) {
    colv[si] = wc * 64 + si * 32 + (lane & 31);
    bv[si] = bias[colv[si]];
  }
#pragma unroll
  for (int ri = 0; ri < 4; ++ri)
#pragma unroll
    for (int r = 0; r < 16; ++r) {
      int row = bm * 256 + wr * 128 + ri * 32 + (r & 3) + 8 * (r >> 2) + 4 * (lane >> 5);
      int yv = (int)y_in[row];
#pragma unroll
      for (int si = 0; si < 2; ++si) {
        if ((colv[si] >> 4) == yv)
          z_out[(size_t)row * 16 + (colv[si] & 15)] = acc[ri][si][r] + bv[si];
      }
    }
}

// H1: logits[65536,16] = (mh+ml) @ (wch+wcl)^T + bc via 3-term 16x16x32 MFMA,
// then per-row argmax -> y. Unchanged.
__global__ __launch_bounds__(256) void logits_kernel(
    const unsigned short* __restrict__ mh, const unsigned short* __restrict__ ml,
    const unsigned short* __restrict__ wch, const unsigned short* __restrict__ wcl,
    const float* __restrict__ bc, float* __restrict__ y_out) {
  __shared__ unsigned short smh[64][LDT], sml[64][LDT];
  __shared__ float slog[64][17];
  const int tid = threadIdx.x;
  const int lane = tid & 63;
  const int wid = tid >> 6;
  const size_t row0 = (size_t)blockIdx.x * 64;
  const int fr = lane & 15;
  const int fq = lane >> 4;

  floatx4 acc = {0.f, 0.f, 0.f, 0.f};
  const unsigned short* bh = wch + fr * 512 + fq * 8;
  const unsigned short* bl = wcl + fr * 512 + fq * 8;

  for (int k0 = 0; k0 < 512; k0 += 32) {
    {
      int row = tid >> 2, cc = (tid & 3) * 8;
      size_t g = (row0 + row) * 512 + k0 + cc;
      *(short8*)&smh[row][cc] = *(const short8*)(mh + g);
      *(short8*)&sml[row][cc] = *(const short8*)(ml + g);
    }
    __syncthreads();
    short8 ah = *(const short8*)&smh[wid * 16 + fr][fq * 8];
    short8 al = *(const short8*)&sml[wid * 16 + fr][fq * 8];
    short8 fbh = *(const short8*)(bh + k0);
    short8 fbl = *(const short8*)(bl + k0);
    acc = __builtin_amdgcn_mfma_f32_16x16x32_bf16(ah, fbh, acc, 0, 0, 0);
    acc = __builtin_amdgcn_mfma_f32_16x16x32_bf16(ah, fbl, acc, 0, 0, 0);
    acc = __builtin_amdgcn_mfma_f32_16x16x32_bf16(al, fbh, acc, 0, 0, 0);
    __syncthreads();
  }
#pragma unroll
  for (int r = 0; r < 4; ++r)
    slog[wid * 16 + fq * 4 + r][fr] = acc[r] + bc[fr];
  __syncthreads();
  if (tid < 64) {
    float best = slog[tid][0];
    int bi = 0;
#pragma unroll
    for (int j = 1; j < 16; ++j) {
      float v = slog[tid][j];
      if (v > best) { best = v; bi = j; }
    }
    y_out[row0 + tid] = (float)bi;
  }
}

// prep: Wg[16,32,512] mu-rows -> wgh[256,512] bf16; wgb[col]=bg[col/16,col%16]
__global__ __launch_bounds__(256) void prep_wg(
    const float* __restrict__ Wg, const float* __restrict__ bg,
    unsigned short* __restrict__ wgh, float* __restrict__ wgb) {
  int gid = blockIdx.x * 256 + threadIdx.x;
  if (gid >= 32768) return;
  int r = gid >> 7;
  int c4 = (gid & 127) * 4;
  int k = r >> 4, e = r & 15;
  float4 v = *(const float4*)(Wg + ((size_t)k * 32 + e) * 512 + c4);
  ushort4 h;
  h.x = bf16_rn(v.x); h.y = bf16_rn(v.y); h.z = bf16_rn(v.z); h.w = bf16_rn(v.w);
  *(ushort4*)(wgh + (size_t)r * 512 + c4) = h;
  if (c4 == 0) wgb[r] = bg[k * 32 + e];
}

extern "C" void kernel_launch(void* const* d_in, const int* in_sizes, int n_in,
                              void* d_out, int out_size, void* d_ws, size_t ws_size,
                              hipStream_t stream) {
  const float* x  = (const float*)d_in[0];
  const float* W0 = (const float*)d_in[1];
  const float* b0 = (const float*)d_in[2];
  const float* W1 = (const float*)d_in[3];
  const float* b1 = (const float*)d_in[4];
  const float* W2 = (const float*)d_in[5];
  const float* b2 = (const float*)d_in[6];
  const float* Wc = (const float*)d_in[7];
  const float* bc = (const float*)d_in[8];
  const float* Wg = (const float*)d_in[9];
  const float* bg = (const float*)d_in[10];

  const size_t NEL = (size_t)MM * KK;
  unsigned short* Ah = (unsigned short*)d_ws;           // 64 MiB each
  unsigned short* Al = Ah + NEL;
  unsigned short* Bh = Al + NEL;
  unsigned short* Bl = Bh + NEL;
  // After GEMM3 (out: Bh/Bl = m-split), Ah/Al regions are free:
  unsigned short* wch = Al;                             // 16 KB
  unsigned short* wcl = Al + 8192;                      // 16 KB
  unsigned short* wgh = Al + 16384;                     // 256 KB
  float* wgb = (float*)(Al + 16384 + 131072);           // 1 KB

  // W-layer splits staged in d_out (3 MiB < 4.5 MiB); dead once GEMM3 done,
  // then overwritten by z (gemm_muz).
  unsigned short* w0h = (unsigned short*)d_out;
  unsigned short* w0l = w0h + 262144;
  unsigned short* w1h = w0l + 262144;
  unsigned short* w1l = w1h + 262144;
  unsigned short* w2h = w1l + 262144;
  unsigned short* w2l = w2h + 262144;

  float* z_out = (float*)d_out;
  float* y_out = z_out + (size_t)MM * 16;               // at +4 MiB, clear of w-splits

  split_kernel<<<256, 256, 0, stream>>>(W0, w0h, w0l, 65536);
  split_kernel<<<256, 256, 0, stream>>>(W1, w1h, w1l, 65536);
  split_kernel<<<256, 256, 0, stream>>>(W2, w2h, w2l, 65536);

  const int ngrid = (MM / 256) * (NN / 256);            // 512, %8==0
  gemm_x<<<ngrid, 512, 0, stream>>>(x, w0h, w0l, b0, Bh, Bl);
  gemm_mfma<true ><<<ngrid, 512, 0, stream>>>(Bh, Bl, w1h, w1l, b1, Ah, Al);
  gemm_mfma<false><<<ngrid, 512, 0, stream>>>(Ah, Al, w2h, w2l, b2, Bh, Bl);

  // head preps (Ah/Al free from here)
  split_kernel<<<8, 256, 0, stream>>>(Wc, wch, wcl, 2048);
  prep_wg<<<128, 256, 0, stream>>>(Wg, bg, wgh, wgb);

  logits_kernel<<<MM / 64, 256, 0, stream>>>(Bh, Bl, wch, wcl, bc, y_out);
  gemm_muz<<<MM / 256, 512, 0, stream>>>(Bh, wgh, wgb, y_out, z_out);
}